// Round 1
// baseline (339.610 us; speedup 1.0000x reference)
//
#include <hip/hip_runtime.h>

// Problem constants (B=2,S=1024 -> T=2048; H=1024, I=512, SI=2048, E=8, TOPK=2)
#define T_TOK 2048
#define H_DIM 1024
#define I_DIM 512
#define SI_DIM 2048
#define E_NUM 8
#define ECAP 2048  // per-expert slot capacity (worst case all tokens -> one expert)

typedef __attribute__((ext_vector_type(8))) short short8;   // 8 x bf16 (4 VGPRs)
typedef __attribute__((ext_vector_type(4))) float floatx4;  // MFMA C/D

// fp32 -> bf16 round-to-nearest-even (inputs are finite; no NaN path needed)
__device__ inline unsigned short f2bf(float f) {
  unsigned u = __builtin_bit_cast(unsigned, f);
  u = (u + 0x7FFFu + ((u >> 16) & 1u)) >> 16;
  return (unsigned short)u;
}

// async global->LDS, 16B per lane; LDS dest = wave-uniform base + lane*16
__device__ inline void gl_lds16(const void* g, void* l) {
  __builtin_amdgcn_global_load_lds(
      (const __attribute__((address_space(1))) unsigned int*)g,
      (__attribute__((address_space(3))) unsigned int*)l, 16, 0, 0);
}

// ---------------------------------------------------------------------------
// Cast all fp32 inputs needed in bf16 form. 6 segments, 4 elems/thread.
// ---------------------------------------------------------------------------
__global__ void cast_all(const float* __restrict__ s0, const float* __restrict__ s1,
                         const float* __restrict__ s2, const float* __restrict__ s3,
                         const float* __restrict__ s4, const float* __restrict__ s5,
                         unsigned short* __restrict__ d0, unsigned short* __restrict__ d1,
                         unsigned short* __restrict__ d2, unsigned short* __restrict__ d3,
                         unsigned short* __restrict__ d4, unsigned short* __restrict__ d5) {
  long g = (long)blockIdx.x * blockDim.x + threadIdx.x;  // group of 4 elems
  const float* s;
  unsigned short* d;
  long off;
  if (g < 524288L)       { s = s0; d = d0; off = g; }            // x: 2,097,152
  else if (g < 2621440L) { s = s1; d = d1; off = g - 524288L; }  // gate_up: 8,388,608
  else if (g < 3670016L) { s = s2; d = d2; off = g - 2621440L; } // down: 4,194,304
  else if (g < 4194304L) { s = s3; d = d3; off = g - 3670016L; } // shared_gate
  else if (g < 4718592L) { s = s4; d = d4; off = g - 4194304L; } // shared_up
  else                   { s = s5; d = d5; off = g - 4718592L; } // shared_down
  float4 v = ((const float4*)s)[off];
  ushort4 o;
  o.x = f2bf(v.x); o.y = f2bf(v.y); o.z = f2bf(v.z); o.w = f2bf(v.w);
  ((ushort4*)d)[off] = o;
}

// ---------------------------------------------------------------------------
// Router: one wave per token. fp32 logits (matches reference numerics),
// top-2 with lowest-index tie-break, renormalized weights, slot assignment,
// sigmoid shared-expert gate.
// ---------------------------------------------------------------------------
__global__ void router_kernel(const float* __restrict__ x,
                              const float* __restrict__ rw,
                              const float* __restrict__ segw,
                              int* __restrict__ cnt,
                              int* __restrict__ slot_token,
                              float* __restrict__ slot_w,
                              float* __restrict__ sg) {
  int t = blockIdx.x * 4 + (threadIdx.x >> 6);
  int lane = threadIdx.x & 63;
  const float* xt = x + (long)t * H_DIM;
  float xv[16];
#pragma unroll
  for (int j = 0; j < 16; ++j) xv[j] = xt[j * 64 + lane];
  float dots[9];
#pragma unroll
  for (int e = 0; e < 8; ++e) {
    const float* w = rw + e * H_DIM;
    float s = 0.f;
#pragma unroll
    for (int j = 0; j < 16; ++j) s += xv[j] * w[j * 64 + lane];
    dots[e] = s;
  }
  {
    float s = 0.f;
#pragma unroll
    for (int j = 0; j < 16; ++j) s += xv[j] * segw[j * 64 + lane];
    dots[8] = s;
  }
#pragma unroll
  for (int off = 32; off > 0; off >>= 1) {
#pragma unroll
    for (int e = 0; e < 9; ++e) dots[e] += __shfl_xor(dots[e], off, 64);
  }
  if (lane == 0) {
    int e0 = 0;
    for (int e = 1; e < 8; ++e)
      if (dots[e] > dots[e0]) e0 = e;
    int e1 = (e0 == 0) ? 1 : 0;
    for (int e = 0; e < 8; ++e)
      if (e != e0 && dots[e] > dots[e1]) e1 = e;
    // softmax denominator cancels in top-2 renormalization
    float p1 = expf(dots[e1] - dots[e0]);
    float w0 = 1.f / (1.f + p1);
    float w1 = p1 / (1.f + p1);
    int pos0 = atomicAdd(&cnt[e0], 1);
    slot_token[e0 * ECAP + pos0] = t;
    slot_w[e0 * ECAP + pos0] = w0;
    int pos1 = atomicAdd(&cnt[e1], 1);
    slot_token[e1 * ECAP + pos1] = t;
    slot_w[e1 * ECAP + pos1] = w1;
    sg[t] = 1.f / (1.f + expf(-dots[8]));
  }
}

// ---------------------------------------------------------------------------
// Fused SwiGLU GEMM: act = silu(A@Bg^T) * (A@Bu^T), bf16 in/out, fp32 acc.
// BM=128, BN=64, BK=32, 4 waves (2x2), each wave 64x32 = 4x2 MFMA tiles x2 acc.
// GATHER: A rows indirected through slot_token (per-expert token lists).
// ---------------------------------------------------------------------------
template <bool GATHER>
__global__ __launch_bounds__(256, 2) void swiglu_gemm(
    const unsigned short* __restrict__ A,   // [rows, K] bf16
    const unsigned short* __restrict__ Bg,  // gate weights [N,K] (+e*estrideB)
    const unsigned short* __restrict__ Bu,  // up weights   [N,K] (+e*estrideB)
    unsigned short* __restrict__ Out,       // [(e*ECAP)+m, N] bf16
    const int* __restrict__ slot_token, const int* __restrict__ cnt,
    int M, int N, int K, long estrideB) {
  const int BM = 128, BN = 64, BK = 32;
  const int tid = threadIdx.x;
  const int lane = tid & 63;
  const int wid = tid >> 6;
  const int wm = wid & 1;   // wave row (64 rows)
  const int wn = wid >> 1;  // wave col (32 cols)
  const int e = blockIdx.z;
  const int m0 = blockIdx.y * BM;
  const int n0 = blockIdx.x * BN;
  int Meff = M;
  if (GATHER) {
    Meff = cnt[e];
    if (m0 >= Meff) return;
  }
  const unsigned short* BgE = Bg + (long)e * estrideB;
  const unsigned short* BuE = Bu + (long)e * estrideB;

  __shared__ __align__(16) unsigned short As[BM * BK];
  __shared__ __align__(16) unsigned short Bgs[BN * BK];
  __shared__ __align__(16) unsigned short Bus[BN * BK];

  const int lrow = lane >> 2;        // 16 rows / chunk
  const int lcol = (lane & 3) * 16;  // byte offset in 64B row

  // per-lane global pointers (fixed across K loop)
  const char* aP[2];
#pragma unroll
  for (int i = 0; i < 2; ++i) {
    int m = m0 + wid * 32 + i * 16 + lrow;
    long row;
    if (GATHER) {
      int mm = (m < Meff - 1) ? m : (Meff - 1);  // clamp tail rows to a valid slot
      row = slot_token[(long)e * ECAP + mm];
    } else {
      row = m;
    }
    aP[i] = (const char*)A + row * (long)(K * 2) + lcol;
  }
  int nb = n0 + wid * 16 + lrow;
  const char* bgP = (const char*)BgE + (long)nb * (K * 2) + lcol;
  const char* buP = (const char*)BuE + (long)nb * (K * 2) + lcol;

  unsigned short* asW0 = &As[(wid * 32) * BK];
  unsigned short* asW1 = &As[(wid * 32 + 16) * BK];
  unsigned short* bgW = &Bgs[(wid * 16) * BK];
  unsigned short* buW = &Bus[(wid * 16) * BK];

  floatx4 accG[4][2], accU[4][2];
  floatx4 zero = {0.f, 0.f, 0.f, 0.f};
#pragma unroll
  for (int i = 0; i < 4; ++i)
#pragma unroll
    for (int j = 0; j < 2; ++j) {
      accG[i][j] = zero;
      accU[i][j] = zero;
    }

  const int ar = lane & 15;
  const int ak = (lane >> 4) * 8;

  for (int k0 = 0; k0 < K; k0 += BK) {
    gl_lds16(aP[0] + (long)k0 * 2, asW0);
    gl_lds16(aP[1] + (long)k0 * 2, asW1);
    gl_lds16(bgP + (long)k0 * 2, bgW);
    gl_lds16(buP + (long)k0 * 2, buW);
    __syncthreads();
    short8 af[4], bgf[2], buf2[2];
#pragma unroll
    for (int tm = 0; tm < 4; ++tm)
      af[tm] = *(const short8*)&As[(wm * 64 + tm * 16 + ar) * BK + ak];
#pragma unroll
    for (int tn = 0; tn < 2; ++tn) {
      bgf[tn] = *(const short8*)&Bgs[(wn * 32 + tn * 16 + ar) * BK + ak];
      buf2[tn] = *(const short8*)&Bus[(wn * 32 + tn * 16 + ar) * BK + ak];
    }
#pragma unroll
    for (int tm = 0; tm < 4; ++tm)
#pragma unroll
      for (int tn = 0; tn < 2; ++tn) {
        accG[tm][tn] = __builtin_amdgcn_mfma_f32_16x16x32_bf16(af[tm], bgf[tn], accG[tm][tn], 0, 0, 0);
        accU[tm][tn] = __builtin_amdgcn_mfma_f32_16x16x32_bf16(af[tm], buf2[tn], accU[tm][tn], 0, 0, 0);
      }
    __syncthreads();
  }

  long outBase = (long)e * ECAP;
#pragma unroll
  for (int tm = 0; tm < 4; ++tm)
#pragma unroll
    for (int tn = 0; tn < 2; ++tn)
#pragma unroll
      for (int r = 0; r < 4; ++r) {
        int row = m0 + wm * 64 + tm * 16 + (lane >> 4) * 4 + r;
        int col = n0 + wn * 32 + tn * 16 + (lane & 15);
        if (!GATHER || row < Meff) {
          float g = accG[tm][tn][r];
          float u = accU[tm][tn][r];
          float act = g / (1.f + expf(-g)) * u;
          Out[(outBase + row) * (long)N + col] = f2bf(act);
        }
      }
}

// ---------------------------------------------------------------------------
// Down-proj GEMM: C = A@B^T. MODE 0: out[t][h] = sg[t]*c (shared path, plain
// store, runs FIRST). MODE 1: atomicAdd(out[token][h], w_slot*c) (expert path).
// BM=BN=128, BK=32, 4 waves (2x2), 4x4 MFMA tiles/wave (m97 structure).
// ---------------------------------------------------------------------------
template <int MODE>
__global__ __launch_bounds__(256, 2) void down_gemm(
    const unsigned short* __restrict__ A,  // [(e*ECAP)+m, K] bf16
    const unsigned short* __restrict__ B,  // [N,K] bf16 (+e*estrideB)
    float* __restrict__ Out,               // [T, H] fp32
    const float* __restrict__ sg, const int* __restrict__ slot_token,
    const float* __restrict__ slot_w, const int* __restrict__ cnt,
    int M, int N, int K, long estrideB) {
  const int BM = 128, BN = 128, BK = 32;
  const int tid = threadIdx.x;
  const int lane = tid & 63;
  const int wid = tid >> 6;
  const int wm = wid & 1;
  const int wn = wid >> 1;
  const int e = blockIdx.z;
  const int m0 = blockIdx.y * BM;
  const int n0 = blockIdx.x * BN;
  int Meff = M;
  if (MODE == 1) {
    Meff = cnt[e];
    if (m0 >= Meff) return;
  }
  const unsigned short* BE = B + (long)e * estrideB;
  const unsigned short* AE = A + (long)e * ECAP * K;

  __shared__ __align__(16) unsigned short As[BM * BK];
  __shared__ __align__(16) unsigned short Bs[BN * BK];

  const int lrow = lane >> 2;
  const int lcol = (lane & 3) * 16;

  const char* aP[2];
  const char* bP[2];
#pragma unroll
  for (int i = 0; i < 2; ++i) {
    int m = m0 + wid * 32 + i * 16 + lrow;
    aP[i] = (const char*)AE + (long)m * (K * 2) + lcol;
    int n = n0 + wid * 32 + i * 16 + lrow;
    bP[i] = (const char*)BE + (long)n * (K * 2) + lcol;
  }
  unsigned short* asW[2] = {&As[(wid * 32) * BK], &As[(wid * 32 + 16) * BK]};
  unsigned short* bsW[2] = {&Bs[(wid * 32) * BK], &Bs[(wid * 32 + 16) * BK]};

  floatx4 acc[4][4];
  floatx4 zero = {0.f, 0.f, 0.f, 0.f};
#pragma unroll
  for (int i = 0; i < 4; ++i)
#pragma unroll
    for (int j = 0; j < 4; ++j) acc[i][j] = zero;

  const int ar = lane & 15;
  const int ak = (lane >> 4) * 8;

  for (int k0 = 0; k0 < K; k0 += BK) {
    gl_lds16(aP[0] + (long)k0 * 2, asW[0]);
    gl_lds16(aP[1] + (long)k0 * 2, asW[1]);
    gl_lds16(bP[0] + (long)k0 * 2, bsW[0]);
    gl_lds16(bP[1] + (long)k0 * 2, bsW[1]);
    __syncthreads();
    short8 af[4], bf[4];
#pragma unroll
    for (int tm = 0; tm < 4; ++tm)
      af[tm] = *(const short8*)&As[(wm * 64 + tm * 16 + ar) * BK + ak];
#pragma unroll
    for (int tn = 0; tn < 4; ++tn)
      bf[tn] = *(const short8*)&Bs[(wn * 64 + tn * 16 + ar) * BK + ak];
#pragma unroll
    for (int tm = 0; tm < 4; ++tm)
#pragma unroll
      for (int tn = 0; tn < 4; ++tn)
        acc[tm][tn] = __builtin_amdgcn_mfma_f32_16x16x32_bf16(af[tm], bf[tn], acc[tm][tn], 0, 0, 0);
    __syncthreads();
  }

#pragma unroll
  for (int tm = 0; tm < 4; ++tm)
#pragma unroll
    for (int tn = 0; tn < 4; ++tn)
#pragma unroll
      for (int r = 0; r < 4; ++r) {
        int row = m0 + wm * 64 + tm * 16 + (lane >> 4) * 4 + r;
        int col = n0 + wn * 64 + tn * 16 + (lane & 15);
        float v = acc[tm][tn][r];
        if (MODE == 0) {
          Out[(long)row * N + col] = sg[row] * v;
        } else if (row < Meff) {
          long slot = (long)e * ECAP + row;
          atomicAdd(&Out[(long)slot_token[slot] * N + col], slot_w[slot] * v);
        }
      }
}

// ---------------------------------------------------------------------------
// Launch. Workspace map (bytes):
//   0        xb       bf16[2048][1024]      4,194,304
//   4194304  gup_b    bf16[8][1024][1024]  16,777,216
//  20971520  down_b   bf16[8][1024][512]    8,388,608
//  29360128  sgate_b  bf16[2048][1024]      4,194,304
//  33554432  sup_b    bf16[2048][1024]      4,194,304
//  37748736  sdown_b  bf16[1024][2048]      4,194,304
//  41943040  act_s    bf16[2048][2048]      8,388,608
//  50331648  act_e    bf16[8*2048][512]    16,777,216
//  67108864  sg       f32[2048]                 8,192
//  67117056  cnt      int[8] (pad 256)            256
//  67117312  slot_token int[8*2048]            65,536
//  67182848  slot_w   f32[8*2048]              65,536
//  total ~64.1 MB
// ---------------------------------------------------------------------------
extern "C" void kernel_launch(void* const* d_in, const int* in_sizes, int n_in,
                              void* d_out, int out_size, void* d_ws, size_t ws_size,
                              hipStream_t stream) {
  const float* x = (const float*)d_in[0];
  const float* rw = (const float*)d_in[1];
  const float* gup = (const float*)d_in[2];
  const float* dwn = (const float*)d_in[3];
  const float* sgw = (const float*)d_in[4];
  const float* suw = (const float*)d_in[5];
  const float* sdw = (const float*)d_in[6];
  const float* segw = (const float*)d_in[7];
  float* out = (float*)d_out;

  char* w = (char*)d_ws;
  unsigned short* xb = (unsigned short*)(w + 0);
  unsigned short* gup_b = (unsigned short*)(w + 4194304L);
  unsigned short* down_b = (unsigned short*)(w + 20971520L);
  unsigned short* sgate_b = (unsigned short*)(w + 29360128L);
  unsigned short* sup_b = (unsigned short*)(w + 33554432L);
  unsigned short* sdown_b = (unsigned short*)(w + 37748736L);
  unsigned short* act_s = (unsigned short*)(w + 41943040L);
  unsigned short* act_e = (unsigned short*)(w + 50331648L);
  float* sg = (float*)(w + 67108864L);
  int* cnt = (int*)(w + 67117056L);
  int* slot_token = (int*)(w + 67117312L);
  float* slot_w = (float*)(w + 67182848L);

  hipMemsetAsync(cnt, 0, E_NUM * sizeof(int), stream);
  cast_all<<<20480, 256, 0, stream>>>(x, gup, dwn, sgw, suw, sdw, xb, gup_b,
                                      down_b, sgate_b, sup_b, sdown_b);
  router_kernel<<<512, 256, 0, stream>>>(x, rw, segw, cnt, slot_token, slot_w, sg);
  // shared SwiGLU: [2048,1024] x [2048,1024]^T (gate & up) -> act_s [2048,2048]
  swiglu_gemm<false><<<dim3(32, 16, 1), 256, 0, stream>>>(
      xb, sgate_b, sup_b, act_s, nullptr, nullptr, 2048, SI_DIM, H_DIM, 0);
  // expert SwiGLU: gathered tokens x gate_up_proj[e] -> act_e [e*2048+m, 512]
  swiglu_gemm<true><<<dim3(8, 16, 8), 256, 0, stream>>>(
      xb, gup_b, gup_b + (long)I_DIM * H_DIM, act_e, slot_token, cnt, ECAP,
      I_DIM, H_DIM, (long)2 * I_DIM * H_DIM);
  // shared down: act_s [2048,2048] x sdown [1024,2048]^T -> out = sg*val (store)
  down_gemm<0><<<dim3(8, 16, 1), 256, 0, stream>>>(
      act_s, sdown_b, out, sg, nullptr, nullptr, nullptr, 2048, H_DIM, SI_DIM, 0);
  // expert down: act_e x down_proj[e]^T -> out += w_slot*val (atomic)
  down_gemm<1><<<dim3(8, 16, 8), 256, 0, stream>>>(
      act_e, down_b, out, nullptr, slot_token, slot_w, cnt, ECAP, H_DIM, I_DIM,
      (long)H_DIM * I_DIM);
}

// Round 2
// 295.937 us; speedup vs baseline: 1.1476x; 1.1476x over previous
//
#include <hip/hip_runtime.h>

// Problem constants (B=2,S=1024 -> T=2048; H=1024, I=512, SI=2048, E=8, TOPK=2)
#define T_TOK 2048
#define H_DIM 1024
#define I_DIM 512
#define SI_DIM 2048
#define E_NUM 8
#define ECAP 2048  // per-expert slot capacity (worst case all tokens -> one expert)

typedef __attribute__((ext_vector_type(8))) short short8;   // 8 x bf16 (4 VGPRs)
typedef __attribute__((ext_vector_type(4))) float floatx4;  // MFMA C/D

// fp32 -> bf16 round-to-nearest-even (inputs are finite; no NaN path needed)
__device__ inline unsigned short f2bf(float f) {
  unsigned u = __builtin_bit_cast(unsigned, f);
  u = (u + 0x7FFFu + ((u >> 16) & 1u)) >> 16;
  return (unsigned short)u;
}

// async global->LDS, 16B per lane; LDS dest = wave-uniform base + lane*16
__device__ inline void gl_lds16(const void* g, void* l) {
  __builtin_amdgcn_global_load_lds(
      (const __attribute__((address_space(1))) unsigned int*)g,
      (__attribute__((address_space(3))) unsigned int*)l, 16, 0, 0);
}

// ---------------------------------------------------------------------------
// Cast all fp32 inputs needed in bf16 form. 6 segments, 4 elems/thread.
// ---------------------------------------------------------------------------
__global__ void cast_all(const float* __restrict__ s0, const float* __restrict__ s1,
                         const float* __restrict__ s2, const float* __restrict__ s3,
                         const float* __restrict__ s4, const float* __restrict__ s5,
                         unsigned short* __restrict__ d0, unsigned short* __restrict__ d1,
                         unsigned short* __restrict__ d2, unsigned short* __restrict__ d3,
                         unsigned short* __restrict__ d4, unsigned short* __restrict__ d5) {
  long g = (long)blockIdx.x * blockDim.x + threadIdx.x;  // group of 4 elems
  const float* s;
  unsigned short* d;
  long off;
  if (g < 524288L)       { s = s0; d = d0; off = g; }            // x: 2,097,152
  else if (g < 2621440L) { s = s1; d = d1; off = g - 524288L; }  // gate_up: 8,388,608
  else if (g < 3670016L) { s = s2; d = d2; off = g - 2621440L; } // down: 4,194,304
  else if (g < 4194304L) { s = s3; d = d3; off = g - 3670016L; } // shared_gate
  else if (g < 4718592L) { s = s4; d = d4; off = g - 4194304L; } // shared_up
  else                   { s = s5; d = d5; off = g - 4718592L; } // shared_down
  float4 v = ((const float4*)s)[off];
  ushort4 o;
  o.x = f2bf(v.x); o.y = f2bf(v.y); o.z = f2bf(v.z); o.w = f2bf(v.w);
  ((ushort4*)d)[off] = o;
}

// ---------------------------------------------------------------------------
// Router phase 1: one wave per token. fp32 logits (matches reference
// numerics), top-2 with lowest-index tie-break, renormalized weights.
// NO atomics — writes per-token packed expert pair + weights + sigmoid gate.
// ---------------------------------------------------------------------------
__global__ void router_kernel(const float* __restrict__ x,
                              const float* __restrict__ rw,
                              const float* __restrict__ segw,
                              int* __restrict__ top2,
                              float2* __restrict__ w01,
                              float* __restrict__ sg) {
  int t = blockIdx.x * 4 + (threadIdx.x >> 6);
  int lane = threadIdx.x & 63;
  const float* xt = x + (long)t * H_DIM;
  float xv[16];
#pragma unroll
  for (int j = 0; j < 16; ++j) xv[j] = xt[j * 64 + lane];
  float dots[9];
#pragma unroll
  for (int e = 0; e < 8; ++e) {
    const float* w = rw + e * H_DIM;
    float s = 0.f;
#pragma unroll
    for (int j = 0; j < 16; ++j) s += xv[j] * w[j * 64 + lane];
    dots[e] = s;
  }
  {
    float s = 0.f;
#pragma unroll
    for (int j = 0; j < 16; ++j) s += xv[j] * segw[j * 64 + lane];
    dots[8] = s;
  }
#pragma unroll
  for (int off = 32; off > 0; off >>= 1) {
#pragma unroll
    for (int e = 0; e < 9; ++e) dots[e] += __shfl_xor(dots[e], off, 64);
  }
  if (lane == 0) {
    int e0 = 0;
    for (int e = 1; e < 8; ++e)
      if (dots[e] > dots[e0]) e0 = e;
    int e1 = (e0 == 0) ? 1 : 0;
    for (int e = 0; e < 8; ++e)
      if (e != e0 && dots[e] > dots[e1]) e1 = e;
    // softmax denominator cancels in top-2 renormalization
    float p1 = expf(dots[e1] - dots[e0]);
    float w0 = 1.f / (1.f + p1);
    float w1 = p1 / (1.f + p1);
    top2[t] = e0 | (e1 << 8);
    w01[t] = make_float2(w0, w1);
    sg[t] = 1.f / (1.f + expf(-dots[8]));
  }
}

// ---------------------------------------------------------------------------
// Router phase 2: one block per expert. Block-wide exclusive scan over all
// tokens builds the dense slot list (sorted by token index) without global
// atomic contention. Thread 255 writes cnt[e].
// ---------------------------------------------------------------------------
__global__ __launch_bounds__(256) void build_lists(
    const int* __restrict__ top2, const float2* __restrict__ w01,
    int* __restrict__ cnt, int* __restrict__ slot_token,
    float* __restrict__ slot_w) {
  const int e = blockIdx.x;
  const int tid = threadIdx.x;
  const int lane = tid & 63, wid = tid >> 6;
  __shared__ int wsum[4];
  const int base_t = tid * 8;  // 2048 / 256
  int match = 0;
  float wv[8];
  int mk[8];
  int c = 0;
#pragma unroll
  for (int j = 0; j < 8; ++j) {
    int p = top2[base_t + j];
    float2 w = w01[base_t + j];
    int m = 0;
    float ww = 0.f;
    if ((p & 0xFF) == e) { m = 1; ww = w.x; }
    else if (((p >> 8) & 0xFF) == e) { m = 1; ww = w.y; }
    mk[j] = m;
    wv[j] = ww;
    c += m;
  }
  (void)match;
  // inclusive scan of per-thread counts within each wave
  int inc = c;
#pragma unroll
  for (int off = 1; off < 64; off <<= 1) {
    int n = __shfl_up(inc, off, 64);
    if (lane >= off) inc += n;
  }
  if (lane == 63) wsum[wid] = inc;
  __syncthreads();
  int woff = 0;
  for (int i = 0; i < wid; ++i) woff += wsum[i];
  int pos = woff + inc - c;  // exclusive prefix for this thread
#pragma unroll
  for (int j = 0; j < 8; ++j) {
    if (mk[j]) {
      slot_token[e * ECAP + pos] = base_t + j;
      slot_w[e * ECAP + pos] = wv[j];
      pos++;
    }
  }
  if (tid == 255) cnt[e] = pos;
}

// ---------------------------------------------------------------------------
// Fused SwiGLU GEMM: act = silu(A@Bg^T) * (A@Bu^T), bf16 in/out, fp32 acc.
// BM=128, BN=64, BK=32, 4 waves (2x2), each wave 64x32 = 4x2 MFMA tiles x2 acc.
// GATHER: A rows indirected through slot_token (per-expert token lists).
// ---------------------------------------------------------------------------
template <bool GATHER>
__global__ __launch_bounds__(256, 2) void swiglu_gemm(
    const unsigned short* __restrict__ A,   // [rows, K] bf16
    const unsigned short* __restrict__ Bg,  // gate weights [N,K] (+e*estrideB)
    const unsigned short* __restrict__ Bu,  // up weights   [N,K] (+e*estrideB)
    unsigned short* __restrict__ Out,       // [(e*ECAP)+m, N] bf16
    const int* __restrict__ slot_token, const int* __restrict__ cnt,
    int M, int N, int K, long estrideB) {
  const int BM = 128, BN = 64, BK = 32;
  const int tid = threadIdx.x;
  const int lane = tid & 63;
  const int wid = tid >> 6;
  const int wm = wid & 1;   // wave row (64 rows)
  const int wn = wid >> 1;  // wave col (32 cols)
  const int e = blockIdx.z;
  const int m0 = blockIdx.y * BM;
  const int n0 = blockIdx.x * BN;
  int Meff = M;
  if (GATHER) {
    Meff = cnt[e];
    if (m0 >= Meff) return;
  }
  const unsigned short* BgE = Bg + (long)e * estrideB;
  const unsigned short* BuE = Bu + (long)e * estrideB;

  __shared__ __align__(16) unsigned short As[BM * BK];
  __shared__ __align__(16) unsigned short Bgs[BN * BK];
  __shared__ __align__(16) unsigned short Bus[BN * BK];

  const int lrow = lane >> 2;        // 16 rows / chunk
  const int lcol = (lane & 3) * 16;  // byte offset in 64B row

  // per-lane global pointers (fixed across K loop)
  const char* aP[2];
#pragma unroll
  for (int i = 0; i < 2; ++i) {
    int m = m0 + wid * 32 + i * 16 + lrow;
    long row;
    if (GATHER) {
      int mm = (m < Meff - 1) ? m : (Meff - 1);  // clamp tail rows to a valid slot
      row = slot_token[(long)e * ECAP + mm];
    } else {
      row = m;
    }
    aP[i] = (const char*)A + row * (long)(K * 2) + lcol;
  }
  int nb = n0 + wid * 16 + lrow;
  const char* bgP = (const char*)BgE + (long)nb * (K * 2) + lcol;
  const char* buP = (const char*)BuE + (long)nb * (K * 2) + lcol;

  unsigned short* asW0 = &As[(wid * 32) * BK];
  unsigned short* asW1 = &As[(wid * 32 + 16) * BK];
  unsigned short* bgW = &Bgs[(wid * 16) * BK];
  unsigned short* buW = &Bus[(wid * 16) * BK];

  floatx4 accG[4][2], accU[4][2];
  floatx4 zero = {0.f, 0.f, 0.f, 0.f};
#pragma unroll
  for (int i = 0; i < 4; ++i)
#pragma unroll
    for (int j = 0; j < 2; ++j) {
      accG[i][j] = zero;
      accU[i][j] = zero;
    }

  const int ar = lane & 15;
  const int ak = (lane >> 4) * 8;

  for (int k0 = 0; k0 < K; k0 += BK) {
    gl_lds16(aP[0] + (long)k0 * 2, asW0);
    gl_lds16(aP[1] + (long)k0 * 2, asW1);
    gl_lds16(bgP + (long)k0 * 2, bgW);
    gl_lds16(buP + (long)k0 * 2, buW);
    __syncthreads();
    short8 af[4], bgf[2], buf2[2];
#pragma unroll
    for (int tm = 0; tm < 4; ++tm)
      af[tm] = *(const short8*)&As[(wm * 64 + tm * 16 + ar) * BK + ak];
#pragma unroll
    for (int tn = 0; tn < 2; ++tn) {
      bgf[tn] = *(const short8*)&Bgs[(wn * 32 + tn * 16 + ar) * BK + ak];
      buf2[tn] = *(const short8*)&Bus[(wn * 32 + tn * 16 + ar) * BK + ak];
    }
#pragma unroll
    for (int tm = 0; tm < 4; ++tm)
#pragma unroll
      for (int tn = 0; tn < 2; ++tn) {
        accG[tm][tn] = __builtin_amdgcn_mfma_f32_16x16x32_bf16(af[tm], bgf[tn], accG[tm][tn], 0, 0, 0);
        accU[tm][tn] = __builtin_amdgcn_mfma_f32_16x16x32_bf16(af[tm], buf2[tn], accU[tm][tn], 0, 0, 0);
      }
    __syncthreads();
  }

  long outBase = (long)e * ECAP;
#pragma unroll
  for (int tm = 0; tm < 4; ++tm)
#pragma unroll
    for (int tn = 0; tn < 2; ++tn)
#pragma unroll
      for (int r = 0; r < 4; ++r) {
        int row = m0 + wm * 64 + tm * 16 + (lane >> 4) * 4 + r;
        int col = n0 + wn * 32 + tn * 16 + (lane & 15);
        if (!GATHER || row < Meff) {
          float g = accG[tm][tn][r];
          float u = accU[tm][tn][r];
          float act = g / (1.f + expf(-g)) * u;
          Out[(outBase + row) * (long)N + col] = f2bf(act);
        }
      }
}

// ---------------------------------------------------------------------------
// Down-proj GEMM: C = A@B^T. MODE 0: out[t][h] = sg[t]*c (shared path, plain
// store, runs FIRST). MODE 1: atomicAdd(out[token][h], w_slot*c) (expert path).
// BM=BN=128, BK=32, 4 waves (2x2), 4x4 MFMA tiles/wave (m97 structure).
// ---------------------------------------------------------------------------
template <int MODE>
__global__ __launch_bounds__(256, 2) void down_gemm(
    const unsigned short* __restrict__ A,  // [(e*ECAP)+m, K] bf16
    const unsigned short* __restrict__ B,  // [N,K] bf16 (+e*estrideB)
    float* __restrict__ Out,               // [T, H] fp32
    const float* __restrict__ sg, const int* __restrict__ slot_token,
    const float* __restrict__ slot_w, const int* __restrict__ cnt,
    int M, int N, int K, long estrideB) {
  const int BM = 128, BN = 128, BK = 32;
  const int tid = threadIdx.x;
  const int lane = tid & 63;
  const int wid = tid >> 6;
  const int wm = wid & 1;
  const int wn = wid >> 1;
  const int e = blockIdx.z;
  const int m0 = blockIdx.y * BM;
  const int n0 = blockIdx.x * BN;
  int Meff = M;
  if (MODE == 1) {
    Meff = cnt[e];
    if (m0 >= Meff) return;
  }
  const unsigned short* BE = B + (long)e * estrideB;
  const unsigned short* AE = A + (long)e * ECAP * K;

  __shared__ __align__(16) unsigned short As[BM * BK];
  __shared__ __align__(16) unsigned short Bs[BN * BK];

  const int lrow = lane >> 2;
  const int lcol = (lane & 3) * 16;

  const char* aP[2];
  const char* bP[2];
#pragma unroll
  for (int i = 0; i < 2; ++i) {
    int m = m0 + wid * 32 + i * 16 + lrow;
    aP[i] = (const char*)AE + (long)m * (K * 2) + lcol;
    int n = n0 + wid * 32 + i * 16 + lrow;
    bP[i] = (const char*)BE + (long)n * (K * 2) + lcol;
  }
  unsigned short* asW[2] = {&As[(wid * 32) * BK], &As[(wid * 32 + 16) * BK]};
  unsigned short* bsW[2] = {&Bs[(wid * 32) * BK], &Bs[(wid * 32 + 16) * BK]};

  floatx4 acc[4][4];
  floatx4 zero = {0.f, 0.f, 0.f, 0.f};
#pragma unroll
  for (int i = 0; i < 4; ++i)
#pragma unroll
    for (int j = 0; j < 4; ++j) acc[i][j] = zero;

  const int ar = lane & 15;
  const int ak = (lane >> 4) * 8;

  for (int k0 = 0; k0 < K; k0 += BK) {
    gl_lds16(aP[0] + (long)k0 * 2, asW[0]);
    gl_lds16(aP[1] + (long)k0 * 2, asW[1]);
    gl_lds16(bP[0] + (long)k0 * 2, bsW[0]);
    gl_lds16(bP[1] + (long)k0 * 2, bsW[1]);
    __syncthreads();
    short8 af[4], bf[4];
#pragma unroll
    for (int tm = 0; tm < 4; ++tm)
      af[tm] = *(const short8*)&As[(wm * 64 + tm * 16 + ar) * BK + ak];
#pragma unroll
    for (int tn = 0; tn < 4; ++tn)
      bf[tn] = *(const short8*)&Bs[(wn * 64 + tn * 16 + ar) * BK + ak];
#pragma unroll
    for (int tm = 0; tm < 4; ++tm)
#pragma unroll
      for (int tn = 0; tn < 4; ++tn)
        acc[tm][tn] = __builtin_amdgcn_mfma_f32_16x16x32_bf16(af[tm], bf[tn], acc[tm][tn], 0, 0, 0);
    __syncthreads();
  }

#pragma unroll
  for (int tm = 0; tm < 4; ++tm)
#pragma unroll
    for (int tn = 0; tn < 4; ++tn)
#pragma unroll
      for (int r = 0; r < 4; ++r) {
        int row = m0 + wm * 64 + tm * 16 + (lane >> 4) * 4 + r;
        int col = n0 + wn * 64 + tn * 16 + (lane & 15);
        float v = acc[tm][tn][r];
        if (MODE == 0) {
          Out[(long)row * N + col] = sg[row] * v;
        } else if (row < Meff) {
          long slot = (long)e * ECAP + row;
          atomicAdd(&Out[(long)slot_token[slot] * N + col], slot_w[slot] * v);
        }
      }
}

// ---------------------------------------------------------------------------
// Launch. Workspace map (bytes):
//   0        xb       bf16[2048][1024]      4,194,304
//   4194304  gup_b    bf16[8][1024][1024]  16,777,216
//  20971520  down_b   bf16[8][1024][512]    8,388,608
//  29360128  sgate_b  bf16[2048][1024]      4,194,304
//  33554432  sup_b    bf16[2048][1024]      4,194,304
//  37748736  sdown_b  bf16[1024][2048]      4,194,304
//  41943040  act_s    bf16[2048][2048]      8,388,608
//  50331648  act_e    bf16[8*2048][512]    16,777,216
//  67108864  sg       f32[2048]                 8,192
//  67117056  cnt      int[8] (pad 256)            256
//  67117312  slot_token int[8*2048]            65,536
//  67182848  slot_w   f32[8*2048]              65,536
//  67248384  top2     int[2048]                 8,192
//  67256576  w01      float2[2048]             16,384
//  total ~64.1 MB
// ---------------------------------------------------------------------------
extern "C" void kernel_launch(void* const* d_in, const int* in_sizes, int n_in,
                              void* d_out, int out_size, void* d_ws, size_t ws_size,
                              hipStream_t stream) {
  const float* x = (const float*)d_in[0];
  const float* rw = (const float*)d_in[1];
  const float* gup = (const float*)d_in[2];
  const float* dwn = (const float*)d_in[3];
  const float* sgw = (const float*)d_in[4];
  const float* suw = (const float*)d_in[5];
  const float* sdw = (const float*)d_in[6];
  const float* segw = (const float*)d_in[7];
  float* out = (float*)d_out;

  char* w = (char*)d_ws;
  unsigned short* xb = (unsigned short*)(w + 0);
  unsigned short* gup_b = (unsigned short*)(w + 4194304L);
  unsigned short* down_b = (unsigned short*)(w + 20971520L);
  unsigned short* sgate_b = (unsigned short*)(w + 29360128L);
  unsigned short* sup_b = (unsigned short*)(w + 33554432L);
  unsigned short* sdown_b = (unsigned short*)(w + 37748736L);
  unsigned short* act_s = (unsigned short*)(w + 41943040L);
  unsigned short* act_e = (unsigned short*)(w + 50331648L);
  float* sg = (float*)(w + 67108864L);
  int* cnt = (int*)(w + 67117056L);
  int* slot_token = (int*)(w + 67117312L);
  float* slot_w = (float*)(w + 67182848L);
  int* top2 = (int*)(w + 67248384L);
  float2* w01 = (float2*)(w + 67256576L);

  cast_all<<<20480, 256, 0, stream>>>(x, gup, dwn, sgw, suw, sdw, xb, gup_b,
                                      down_b, sgate_b, sup_b, sdown_b);
  router_kernel<<<512, 256, 0, stream>>>(x, rw, segw, top2, w01, sg);
  build_lists<<<E_NUM, 256, 0, stream>>>(top2, w01, cnt, slot_token, slot_w);
  // shared SwiGLU: [2048,1024] x [2048,1024]^T (gate & up) -> act_s [2048,2048]
  swiglu_gemm<false><<<dim3(32, 16, 1), 256, 0, stream>>>(
      xb, sgate_b, sup_b, act_s, nullptr, nullptr, 2048, SI_DIM, H_DIM, 0);
  // expert SwiGLU: gathered tokens x gate_up_proj[e] -> act_e [e*2048+m, 512]
  swiglu_gemm<true><<<dim3(8, 16, 8), 256, 0, stream>>>(
      xb, gup_b, gup_b + (long)I_DIM * H_DIM, act_e, slot_token, cnt, ECAP,
      I_DIM, H_DIM, (long)2 * I_DIM * H_DIM);
  // shared down: act_s [2048,2048] x sdown [1024,2048]^T -> out = sg*val (store)
  down_gemm<0><<<dim3(8, 16, 1), 256, 0, stream>>>(
      act_s, sdown_b, out, sg, nullptr, nullptr, nullptr, 2048, H_DIM, SI_DIM, 0);
  // expert down: act_e x down_proj[e]^T -> out += w_slot*val (atomic)
  down_gemm<1><<<dim3(8, 16, 8), 256, 0, stream>>>(
      act_e, down_b, out, nullptr, slot_token, slot_w, cnt, ECAP, H_DIM, I_DIM,
      (long)H_DIM * I_DIM);
}

// Round 3
// 269.565 us; speedup vs baseline: 1.2598x; 1.0978x over previous
//
#include <hip/hip_runtime.h>

// Problem constants (B=2,S=1024 -> T=2048; H=1024, I=512, SI=2048, E=8, TOPK=2)
#define T_TOK 2048
#define H_DIM 1024
#define I_DIM 512
#define SI_DIM 2048
#define E_NUM 8
#define NSLOT 4096  // total expert slots: exactly 2 per token

typedef __attribute__((ext_vector_type(8))) short short8;   // 8 x bf16 (4 VGPRs)
typedef __attribute__((ext_vector_type(4))) float floatx4;  // MFMA C/D

// fp32 -> bf16 round-to-nearest-even (inputs are finite; no NaN path needed)
__device__ inline unsigned short f2bf(float f) {
  unsigned u = __builtin_bit_cast(unsigned, f);
  u = (u + 0x7FFFu + ((u >> 16) & 1u)) >> 16;
  return (unsigned short)u;
}
__device__ inline float bf2f(unsigned short u) {
  return __builtin_bit_cast(float, (unsigned)u << 16);
}

// async global->LDS, 16B per lane; LDS dest = wave-uniform base + lane*16
__device__ inline void gl_lds16(const void* g, void* l) {
  __builtin_amdgcn_global_load_lds(
      (const __attribute__((address_space(1))) unsigned int*)g,
      (__attribute__((address_space(3))) unsigned int*)l, 16, 0, 0);
}

// ---------------------------------------------------------------------------
// Cast all fp32 inputs needed in bf16 form. 6 segments, 4 elems/thread.
// ---------------------------------------------------------------------------
__global__ void cast_all(const float* __restrict__ s0, const float* __restrict__ s1,
                         const float* __restrict__ s2, const float* __restrict__ s3,
                         const float* __restrict__ s4, const float* __restrict__ s5,
                         unsigned short* __restrict__ d0, unsigned short* __restrict__ d1,
                         unsigned short* __restrict__ d2, unsigned short* __restrict__ d3,
                         unsigned short* __restrict__ d4, unsigned short* __restrict__ d5) {
  long g = (long)blockIdx.x * blockDim.x + threadIdx.x;  // group of 4 elems
  const float* s;
  unsigned short* d;
  long off;
  if (g < 524288L)       { s = s0; d = d0; off = g; }            // x: 2,097,152
  else if (g < 2621440L) { s = s1; d = d1; off = g - 524288L; }  // gate_up: 8,388,608
  else if (g < 3670016L) { s = s2; d = d2; off = g - 2621440L; } // down: 4,194,304
  else if (g < 4194304L) { s = s3; d = d3; off = g - 3670016L; } // shared_gate
  else if (g < 4718592L) { s = s4; d = d4; off = g - 4194304L; } // shared_up
  else                   { s = s5; d = d5; off = g - 4718592L; } // shared_down
  float4 v = ((const float4*)s)[off];
  ushort4 o;
  o.x = f2bf(v.x); o.y = f2bf(v.y); o.z = f2bf(v.z); o.w = f2bf(v.w);
  ((ushort4*)d)[off] = o;
}

// ---------------------------------------------------------------------------
// Router phase 1: one wave per token. fp32 logits (matches reference
// numerics), top-2 with lowest-index tie-break, renormalized weights.
// NO atomics — writes per-token packed expert pair + weights + sigmoid gate.
// ---------------------------------------------------------------------------
__global__ void router_kernel(const float* __restrict__ x,
                              const float* __restrict__ rw,
                              const float* __restrict__ segw,
                              int* __restrict__ top2,
                              float2* __restrict__ w01,
                              float* __restrict__ sg) {
  int t = blockIdx.x * 4 + (threadIdx.x >> 6);
  int lane = threadIdx.x & 63;
  const float* xt = x + (long)t * H_DIM;
  float xv[16];
#pragma unroll
  for (int j = 0; j < 16; ++j) xv[j] = xt[j * 64 + lane];
  float dots[9];
#pragma unroll
  for (int e = 0; e < 8; ++e) {
    const float* w = rw + e * H_DIM;
    float s = 0.f;
#pragma unroll
    for (int j = 0; j < 16; ++j) s += xv[j] * w[j * 64 + lane];
    dots[e] = s;
  }
  {
    float s = 0.f;
#pragma unroll
    for (int j = 0; j < 16; ++j) s += xv[j] * segw[j * 64 + lane];
    dots[8] = s;
  }
#pragma unroll
  for (int off = 32; off > 0; off >>= 1) {
#pragma unroll
    for (int e = 0; e < 9; ++e) dots[e] += __shfl_xor(dots[e], off, 64);
  }
  if (lane == 0) {
    int e0 = 0;
    for (int e = 1; e < 8; ++e)
      if (dots[e] > dots[e0]) e0 = e;
    int e1 = (e0 == 0) ? 1 : 0;
    for (int e = 0; e < 8; ++e)
      if (e != e0 && dots[e] > dots[e1]) e1 = e;
    // softmax denominator cancels in top-2 renormalization
    float p1 = expf(dots[e1] - dots[e0]);
    float w0 = 1.f / (1.f + p1);
    float w1 = p1 / (1.f + p1);
    top2[t] = e0 | (e1 << 8);
    w01[t] = make_float2(w0, w1);
    sg[t] = 1.f / (1.f + expf(-dots[8]));
  }
}

// ---------------------------------------------------------------------------
// Router phase 2: one block per expert. Block-wide exclusive scan builds the
// COMPACT slot list (global base = #assignments to experts < e, computed from
// the same top2 scan; total slots == 4096 exactly). Also records tok_slot:
// token -> its two compact slot indices (for the fused combine epilogue).
// ---------------------------------------------------------------------------
__global__ __launch_bounds__(256) void build_lists(
    const int* __restrict__ top2, int* __restrict__ cnt, int* __restrict__ ebase,
    int* __restrict__ slot_token, int* __restrict__ tok_slot) {
  const int e = blockIdx.x;
  const int tid = threadIdx.x;
  const int lane = tid & 63, wid = tid >> 6;
  __shared__ int wsum[4], wbelow[4];
  const int base_t = tid * 8;  // 2048 / 256
  int mk[8], kk[8];
  int c = 0, below = 0;
#pragma unroll
  for (int j = 0; j < 8; ++j) {
    int p = top2[base_t + j];
    int e0 = p & 0xFF, e1 = (p >> 8) & 0xFF;
    below += (e0 < e) + (e1 < e);
    int m = 0, k = 0;
    if (e0 == e) { m = 1; k = 0; }
    else if (e1 == e) { m = 1; k = 1; }
    mk[j] = m; kk[j] = k;
    c += m;
  }
  // inclusive scan of per-thread counts within each wave
  int inc = c;
#pragma unroll
  for (int off = 1; off < 64; off <<= 1) {
    int n = __shfl_up(inc, off, 64);
    if (lane >= off) inc += n;
  }
  // wave-sum of 'below'
  int bsum = below;
#pragma unroll
  for (int off = 32; off > 0; off >>= 1) bsum += __shfl_xor(bsum, off, 64);
  if (lane == 63) wsum[wid] = inc;
  if (lane == 0) wbelow[wid] = bsum;
  __syncthreads();
  int woff = 0;
#pragma unroll
  for (int i = 0; i < 4; ++i)
    if (i < wid) woff += wsum[i];
  int baseE = wbelow[0] + wbelow[1] + wbelow[2] + wbelow[3];
  int pos = baseE + woff + inc - c;  // global exclusive prefix for this thread
#pragma unroll
  for (int j = 0; j < 8; ++j) {
    if (mk[j]) {
      slot_token[pos] = base_t + j;
      tok_slot[2 * (base_t + j) + kk[j]] = pos;
      pos++;
    }
  }
  if (tid == 255) cnt[e] = woff + inc;
  if (tid == 0) ebase[e] = baseE;
}

// ---------------------------------------------------------------------------
// Fused SwiGLU GEMM: act = silu(A@Bg^T) * (A@Bu^T), bf16 in/out, fp32 acc.
// BM=128, BN=64, BK=32, 4 waves (2x2), each wave 64x32 = 4x2 MFMA tiles x2 acc.
// GATHER: A rows indirected through compact slot_token; Out rows compact.
// ---------------------------------------------------------------------------
template <bool GATHER>
__global__ __launch_bounds__(256, 2) void swiglu_gemm(
    const unsigned short* __restrict__ A,   // [rows, K] bf16
    const unsigned short* __restrict__ Bg,  // gate weights [N,K] (+e*estrideB)
    const unsigned short* __restrict__ Bu,  // up weights   [N,K] (+e*estrideB)
    unsigned short* __restrict__ Out,       // [baseE+m, N] bf16
    const int* __restrict__ slot_token, const int* __restrict__ cnt,
    const int* __restrict__ ebase, int M, int N, int K, long estrideB) {
  const int BM = 128, BN = 64, BK = 32;
  const int tid = threadIdx.x;
  const int lane = tid & 63;
  const int wid = tid >> 6;
  const int wm = wid & 1;   // wave row (64 rows)
  const int wn = wid >> 1;  // wave col (32 cols)
  const int e = blockIdx.z;
  const int m0 = blockIdx.y * BM;
  const int n0 = blockIdx.x * BN;
  int Meff = M, baseE = 0;
  if (GATHER) {
    Meff = cnt[e];
    if (m0 >= Meff) return;
    baseE = ebase[e];
  }
  const unsigned short* BgE = Bg + (long)e * estrideB;
  const unsigned short* BuE = Bu + (long)e * estrideB;

  __shared__ __align__(16) unsigned short As[BM * BK];
  __shared__ __align__(16) unsigned short Bgs[BN * BK];
  __shared__ __align__(16) unsigned short Bus[BN * BK];

  const int lrow = lane >> 2;        // 16 rows / chunk
  const int lcol = (lane & 3) * 16;  // byte offset in 64B row

  // per-lane global pointers (fixed across K loop)
  const char* aP[2];
#pragma unroll
  for (int i = 0; i < 2; ++i) {
    int m = m0 + wid * 32 + i * 16 + lrow;
    long row;
    if (GATHER) {
      int mm = (m < Meff - 1) ? m : (Meff - 1);  // clamp tail rows to a valid slot
      row = slot_token[baseE + mm];
    } else {
      row = m;
    }
    aP[i] = (const char*)A + row * (long)(K * 2) + lcol;
  }
  int nb = n0 + wid * 16 + lrow;
  const char* bgP = (const char*)BgE + (long)nb * (K * 2) + lcol;
  const char* buP = (const char*)BuE + (long)nb * (K * 2) + lcol;

  unsigned short* asW0 = &As[(wid * 32) * BK];
  unsigned short* asW1 = &As[(wid * 32 + 16) * BK];
  unsigned short* bgW = &Bgs[(wid * 16) * BK];
  unsigned short* buW = &Bus[(wid * 16) * BK];

  floatx4 accG[4][2], accU[4][2];
  floatx4 zero = {0.f, 0.f, 0.f, 0.f};
#pragma unroll
  for (int i = 0; i < 4; ++i)
#pragma unroll
    for (int j = 0; j < 2; ++j) {
      accG[i][j] = zero;
      accU[i][j] = zero;
    }

  const int ar = lane & 15;
  const int ak = (lane >> 4) * 8;

  for (int k0 = 0; k0 < K; k0 += BK) {
    gl_lds16(aP[0] + (long)k0 * 2, asW0);
    gl_lds16(aP[1] + (long)k0 * 2, asW1);
    gl_lds16(bgP + (long)k0 * 2, bgW);
    gl_lds16(buP + (long)k0 * 2, buW);
    __syncthreads();
    short8 af[4], bgf[2], buf2[2];
#pragma unroll
    for (int tm = 0; tm < 4; ++tm)
      af[tm] = *(const short8*)&As[(wm * 64 + tm * 16 + ar) * BK + ak];
#pragma unroll
    for (int tn = 0; tn < 2; ++tn) {
      bgf[tn] = *(const short8*)&Bgs[(wn * 32 + tn * 16 + ar) * BK + ak];
      buf2[tn] = *(const short8*)&Bus[(wn * 32 + tn * 16 + ar) * BK + ak];
    }
#pragma unroll
    for (int tm = 0; tm < 4; ++tm)
#pragma unroll
      for (int tn = 0; tn < 2; ++tn) {
        accG[tm][tn] = __builtin_amdgcn_mfma_f32_16x16x32_bf16(af[tm], bgf[tn], accG[tm][tn], 0, 0, 0);
        accU[tm][tn] = __builtin_amdgcn_mfma_f32_16x16x32_bf16(af[tm], buf2[tn], accU[tm][tn], 0, 0, 0);
      }
    __syncthreads();
  }

#pragma unroll
  for (int tm = 0; tm < 4; ++tm)
#pragma unroll
    for (int tn = 0; tn < 2; ++tn)
#pragma unroll
      for (int r = 0; r < 4; ++r) {
        int row = m0 + wm * 64 + tm * 16 + (lane >> 4) * 4 + r;
        int col = n0 + wn * 32 + tn * 16 + (lane & 15);
        if (!GATHER || row < Meff) {
          float g = accG[tm][tn][r];
          float u = accU[tm][tn][r];
          float act = g / (1.f + expf(-g)) * u;
          Out[(long)(baseE + row) * N + col] = f2bf(act);
        }
      }
}

// ---------------------------------------------------------------------------
// Down-proj GEMM: C = A@B^T. BM=128, BN=64, BK=32, 4 waves, 4x2 tiles/wave.
// MODE 1 (expert, runs FIRST): plain bf16 store to compact eout[slot][h].
// MODE 0 (shared, runs LAST): fused combine epilogue
//   out[t][h] = sg[t]*v + w0*eout[slot0(t)][h] + w1*eout[slot1(t)][h].
// No atomics anywhere.
// ---------------------------------------------------------------------------
template <int MODE>
__global__ __launch_bounds__(256, 2) void down_gemm(
    const unsigned short* __restrict__ A,  // [rows, K] bf16 (compact for MODE1)
    const unsigned short* __restrict__ B,  // [N,K] bf16 (+e*estrideB)
    float* __restrict__ OutF,              // MODE0: [T, H] fp32
    unsigned short* __restrict__ OutB,     // MODE1: eout bf16 [4096, H]
    const float* __restrict__ sg, const float2* __restrict__ w01,
    const int* __restrict__ tok_slot, const unsigned short* __restrict__ eout,
    const int* __restrict__ ebase, const int* __restrict__ cnt,
    int M, int N, int K, long estrideB) {
  const int BM = 128, BN = 64, BK = 32;
  const int tid = threadIdx.x;
  const int lane = tid & 63;
  const int wid = tid >> 6;
  const int wm = wid & 1;
  const int wn = wid >> 1;
  const int e = blockIdx.z;
  const int m0 = blockIdx.y * BM;
  const int n0 = blockIdx.x * BN;
  int Meff = M, baseE = 0;
  if (MODE == 1) {
    Meff = cnt[e];
    if (m0 >= Meff) return;
    baseE = ebase[e];
  }
  const unsigned short* BE = B + (long)e * estrideB;

  __shared__ __align__(16) unsigned short As[BM * BK];
  __shared__ __align__(16) unsigned short Bs[BN * BK];

  const int lrow = lane >> 2;
  const int lcol = (lane & 3) * 16;

  const char* aP[2];
#pragma unroll
  for (int i = 0; i < 2; ++i) {
    int m = m0 + wid * 32 + i * 16 + lrow;
    long arow;
    if (MODE == 1) {
      int mm = (m < Meff - 1) ? m : (Meff - 1);  // clamp tail to valid row
      arow = baseE + mm;
    } else {
      arow = m;
    }
    aP[i] = (const char*)A + arow * (long)(K * 2) + lcol;
  }
  int nb = n0 + wid * 16 + lrow;
  const char* bP = (const char*)BE + (long)nb * (K * 2) + lcol;

  unsigned short* asW0 = &As[(wid * 32) * BK];
  unsigned short* asW1 = &As[(wid * 32 + 16) * BK];
  unsigned short* bsW = &Bs[(wid * 16) * BK];

  floatx4 acc[4][2];
  floatx4 zero = {0.f, 0.f, 0.f, 0.f};
#pragma unroll
  for (int i = 0; i < 4; ++i)
#pragma unroll
    for (int j = 0; j < 2; ++j) acc[i][j] = zero;

  const int ar = lane & 15;
  const int ak = (lane >> 4) * 8;

  for (int k0 = 0; k0 < K; k0 += BK) {
    gl_lds16(aP[0] + (long)k0 * 2, asW0);
    gl_lds16(aP[1] + (long)k0 * 2, asW1);
    gl_lds16(bP + (long)k0 * 2, bsW);
    __syncthreads();
    short8 af[4], bf[2];
#pragma unroll
    for (int tm = 0; tm < 4; ++tm)
      af[tm] = *(const short8*)&As[(wm * 64 + tm * 16 + ar) * BK + ak];
#pragma unroll
    for (int tn = 0; tn < 2; ++tn)
      bf[tn] = *(const short8*)&Bs[(wn * 32 + tn * 16 + ar) * BK + ak];
#pragma unroll
    for (int tm = 0; tm < 4; ++tm)
#pragma unroll
      for (int tn = 0; tn < 2; ++tn)
        acc[tm][tn] = __builtin_amdgcn_mfma_f32_16x16x32_bf16(af[tm], bf[tn], acc[tm][tn], 0, 0, 0);
    __syncthreads();
  }

#pragma unroll
  for (int tm = 0; tm < 4; ++tm)
#pragma unroll
    for (int r = 0; r < 4; ++r) {
      int row = m0 + wm * 64 + tm * 16 + (lane >> 4) * 4 + r;
      if (MODE == 0) {
        float sgr = sg[row];
        float2 wr = w01[row];
        int s0 = tok_slot[2 * row];
        int s1 = tok_slot[2 * row + 1];
#pragma unroll
        for (int tn = 0; tn < 2; ++tn) {
          int col = n0 + wn * 32 + tn * 16 + (lane & 15);
          float v = acc[tm][tn][r];
          float ev0 = bf2f(eout[(long)s0 * N + col]);
          float ev1 = bf2f(eout[(long)s1 * N + col]);
          OutF[(long)row * N + col] = sgr * v + wr.x * ev0 + wr.y * ev1;
        }
      } else {
        if (row < Meff) {
#pragma unroll
          for (int tn = 0; tn < 2; ++tn) {
            int col = n0 + wn * 32 + tn * 16 + (lane & 15);
            OutB[(long)(baseE + row) * N + col] = f2bf(acc[tm][tn][r]);
          }
        }
      }
    }
}

// ---------------------------------------------------------------------------
// Workspace map (bytes):
//   0         xb        bf16[2048][1024]     4,194,304
//   4194304   gup_b     bf16[8][1024][1024] 16,777,216
//  20971520   down_b    bf16[8][1024][512]   8,388,608
//  29360128   sgate_b   bf16[2048][1024]     4,194,304
//  33554432   sup_b     bf16[2048][1024]     4,194,304
//  37748736   sdown_b   bf16[1024][2048]     4,194,304
//  41943040   act_s     bf16[2048][2048]     8,388,608
//  50331648   act_e     bf16[4096][512]      4,194,304   (compact slots)
//  54525952   eout      bf16[4096][1024]     8,388,608   (compact slots)
//  62914560   sg        f32[2048]                8,192
//  62922752   top2      int[2048]                8,192
//  62930944   w01       float2[2048]            16,384
//  62947328   cnt       int[8] (pad)               256
//  62947584   ebase     int[8] (pad)               256
//  62947840   slot_token int[4096]              16,384
//  62964224   tok_slot  int[2048*2]             16,384
//  total ~63.0 MB (< 67.3 MB known-safe from round 1/2)
// ---------------------------------------------------------------------------
extern "C" void kernel_launch(void* const* d_in, const int* in_sizes, int n_in,
                              void* d_out, int out_size, void* d_ws, size_t ws_size,
                              hipStream_t stream) {
  const float* x = (const float*)d_in[0];
  const float* rw = (const float*)d_in[1];
  const float* gup = (const float*)d_in[2];
  const float* dwn = (const float*)d_in[3];
  const float* sgw = (const float*)d_in[4];
  const float* suw = (const float*)d_in[5];
  const float* sdw = (const float*)d_in[6];
  const float* segw = (const float*)d_in[7];
  float* out = (float*)d_out;

  char* w = (char*)d_ws;
  unsigned short* xb = (unsigned short*)(w + 0);
  unsigned short* gup_b = (unsigned short*)(w + 4194304L);
  unsigned short* down_b = (unsigned short*)(w + 20971520L);
  unsigned short* sgate_b = (unsigned short*)(w + 29360128L);
  unsigned short* sup_b = (unsigned short*)(w + 33554432L);
  unsigned short* sdown_b = (unsigned short*)(w + 37748736L);
  unsigned short* act_s = (unsigned short*)(w + 41943040L);
  unsigned short* act_e = (unsigned short*)(w + 50331648L);
  unsigned short* eout = (unsigned short*)(w + 54525952L);
  float* sg = (float*)(w + 62914560L);
  int* top2 = (int*)(w + 62922752L);
  float2* w01 = (float2*)(w + 62930944L);
  int* cnt = (int*)(w + 62947328L);
  int* ebase = (int*)(w + 62947584L);
  int* slot_token = (int*)(w + 62947840L);
  int* tok_slot = (int*)(w + 62964224L);

  cast_all<<<20480, 256, 0, stream>>>(x, gup, dwn, sgw, suw, sdw, xb, gup_b,
                                      down_b, sgate_b, sup_b, sdown_b);
  router_kernel<<<512, 256, 0, stream>>>(x, rw, segw, top2, w01, sg);
  build_lists<<<E_NUM, 256, 0, stream>>>(top2, cnt, ebase, slot_token, tok_slot);
  // shared SwiGLU: [2048,1024] x [2048,1024]^T (gate & up) -> act_s [2048,2048]
  swiglu_gemm<false><<<dim3(32, 16, 1), 256, 0, stream>>>(
      xb, sgate_b, sup_b, act_s, nullptr, nullptr, nullptr, 2048, SI_DIM, H_DIM, 0);
  // expert SwiGLU: gathered tokens x gate_up_proj[e] -> act_e [slot, 512] compact
  swiglu_gemm<true><<<dim3(8, 16, 8), 256, 0, stream>>>(
      xb, gup_b, gup_b + (long)I_DIM * H_DIM, act_e, slot_token, cnt, ebase,
      T_TOK, I_DIM, H_DIM, (long)2 * I_DIM * H_DIM);
  // expert down: act_e x down_proj[e]^T -> eout[slot][h] (plain bf16 store)
  down_gemm<1><<<dim3(16, 16, 8), 256, 0, stream>>>(
      act_e, down_b, nullptr, eout, nullptr, nullptr, nullptr, nullptr, ebase,
      cnt, T_TOK, H_DIM, I_DIM, (long)H_DIM * I_DIM);
  // shared down + combine: act_s x sdown^T; out = sg*v + w0*eout[s0] + w1*eout[s1]
  down_gemm<0><<<dim3(16, 16, 1), 256, 0, stream>>>(
      act_s, sdown_b, out, nullptr, sg, w01, tok_slot, eout, nullptr, nullptr,
      T_TOK, H_DIM, SI_DIM, 0);
}

// Round 4
// 249.240 us; speedup vs baseline: 1.3626x; 1.0815x over previous
//
#include <hip/hip_runtime.h>

// Problem constants (B=2,S=1024 -> T=2048; H=1024, I=512, SI=2048, E=8, TOPK=2)
#define T_TOK 2048
#define H_DIM 1024
#define I_DIM 512
#define SI_DIM 2048
#define E_NUM 8
#define NSLOT 4096  // total expert slots: exactly 2 per token

typedef __attribute__((ext_vector_type(8))) short short8;   // 8 x bf16 (4 VGPRs)
typedef __attribute__((ext_vector_type(4))) float floatx4;  // MFMA C/D

// fp32 -> bf16 round-to-nearest-even (inputs are finite; no NaN path needed)
__device__ inline unsigned short f2bf(float f) {
  unsigned u = __builtin_bit_cast(unsigned, f);
  u = (u + 0x7FFFu + ((u >> 16) & 1u)) >> 16;
  return (unsigned short)u;
}
__device__ inline float bf2f(unsigned short u) {
  return __builtin_bit_cast(float, (unsigned)u << 16);
}

// async global->LDS, 16B per lane; LDS dest = wave-uniform base + lane*16
__device__ inline void gl_lds16(const void* g, void* l) {
  __builtin_amdgcn_global_load_lds(
      (const __attribute__((address_space(1))) unsigned int*)g,
      (__attribute__((address_space(3))) unsigned int*)l, 16, 0, 0);
}

// ---------------------------------------------------------------------------
// Cast all fp32 inputs needed in bf16 form. 6 segments, 4 elems/thread.
// ---------------------------------------------------------------------------
__global__ void cast_all(const float* __restrict__ s0, const float* __restrict__ s1,
                         const float* __restrict__ s2, const float* __restrict__ s3,
                         const float* __restrict__ s4, const float* __restrict__ s5,
                         unsigned short* __restrict__ d0, unsigned short* __restrict__ d1,
                         unsigned short* __restrict__ d2, unsigned short* __restrict__ d3,
                         unsigned short* __restrict__ d4, unsigned short* __restrict__ d5) {
  long g = (long)blockIdx.x * blockDim.x + threadIdx.x;  // group of 4 elems
  const float* s;
  unsigned short* d;
  long off;
  if (g < 524288L)       { s = s0; d = d0; off = g; }            // x
  else if (g < 2621440L) { s = s1; d = d1; off = g - 524288L; }  // gate_up
  else if (g < 3670016L) { s = s2; d = d2; off = g - 2621440L; } // down
  else if (g < 4194304L) { s = s3; d = d3; off = g - 3670016L; } // shared_gate
  else if (g < 4718592L) { s = s4; d = d4; off = g - 4194304L; } // shared_up
  else                   { s = s5; d = d5; off = g - 4718592L; } // shared_down
  float4 v = ((const float4*)s)[off];
  ushort4 o;
  o.x = f2bf(v.x); o.y = f2bf(v.y); o.z = f2bf(v.z); o.w = f2bf(v.w);
  ((ushort4*)d)[off] = o;
}

// ---------------------------------------------------------------------------
// Router phase 1: one wave per token, fp32 logits, top-2 lowest-index
// tie-break, renormalized weights, sigmoid shared gate. No atomics.
// ---------------------------------------------------------------------------
__global__ void router_kernel(const float* __restrict__ x,
                              const float* __restrict__ rw,
                              const float* __restrict__ segw,
                              int* __restrict__ top2,
                              float2* __restrict__ w01,
                              float* __restrict__ sg) {
  int t = blockIdx.x * 4 + (threadIdx.x >> 6);
  int lane = threadIdx.x & 63;
  const float* xt = x + (long)t * H_DIM;
  float xv[16];
#pragma unroll
  for (int j = 0; j < 16; ++j) xv[j] = xt[j * 64 + lane];
  float dots[9];
#pragma unroll
  for (int e = 0; e < 8; ++e) {
    const float* w = rw + e * H_DIM;
    float s = 0.f;
#pragma unroll
    for (int j = 0; j < 16; ++j) s += xv[j] * w[j * 64 + lane];
    dots[e] = s;
  }
  {
    float s = 0.f;
#pragma unroll
    for (int j = 0; j < 16; ++j) s += xv[j] * segw[j * 64 + lane];
    dots[8] = s;
  }
#pragma unroll
  for (int off = 32; off > 0; off >>= 1) {
#pragma unroll
    for (int e = 0; e < 9; ++e) dots[e] += __shfl_xor(dots[e], off, 64);
  }
  if (lane == 0) {
    int e0 = 0;
    for (int e = 1; e < 8; ++e)
      if (dots[e] > dots[e0]) e0 = e;
    int e1 = (e0 == 0) ? 1 : 0;
    for (int e = 0; e < 8; ++e)
      if (e != e0 && dots[e] > dots[e1]) e1 = e;
    float p1 = expf(dots[e1] - dots[e0]);
    float w0 = 1.f / (1.f + p1);
    float w1 = p1 / (1.f + p1);
    top2[t] = e0 | (e1 << 8);
    w01[t] = make_float2(w0, w1);
    sg[t] = 1.f / (1.f + expf(-dots[8]));
  }
}

// ---------------------------------------------------------------------------
// Router phase 2: one block per expert; block-wide scan -> compact slot list
// (global base = #assignments to experts < e) + tok_slot back-pointers.
// ---------------------------------------------------------------------------
__global__ __launch_bounds__(256) void build_lists(
    const int* __restrict__ top2, int* __restrict__ cnt, int* __restrict__ ebase,
    int* __restrict__ slot_token, int* __restrict__ tok_slot) {
  const int e = blockIdx.x;
  const int tid = threadIdx.x;
  const int lane = tid & 63, wid = tid >> 6;
  __shared__ int wsum[4], wbelow[4];
  const int base_t = tid * 8;  // 2048 / 256
  int mk[8], kk[8];
  int c = 0, below = 0;
#pragma unroll
  for (int j = 0; j < 8; ++j) {
    int p = top2[base_t + j];
    int e0 = p & 0xFF, e1 = (p >> 8) & 0xFF;
    below += (e0 < e) + (e1 < e);
    int m = 0, k = 0;
    if (e0 == e) { m = 1; k = 0; }
    else if (e1 == e) { m = 1; k = 1; }
    mk[j] = m; kk[j] = k;
    c += m;
  }
  int inc = c;
#pragma unroll
  for (int off = 1; off < 64; off <<= 1) {
    int n = __shfl_up(inc, off, 64);
    if (lane >= off) inc += n;
  }
  int bsum = below;
#pragma unroll
  for (int off = 32; off > 0; off >>= 1) bsum += __shfl_xor(bsum, off, 64);
  if (lane == 63) wsum[wid] = inc;
  if (lane == 0) wbelow[wid] = bsum;
  __syncthreads();
  int woff = 0;
#pragma unroll
  for (int i = 0; i < 4; ++i)
    if (i < wid) woff += wsum[i];
  int baseE = wbelow[0] + wbelow[1] + wbelow[2] + wbelow[3];
  int pos = baseE + woff + inc - c;
#pragma unroll
  for (int j = 0; j < 8; ++j) {
    if (mk[j]) {
      slot_token[pos] = base_t + j;
      tok_slot[2 * (base_t + j) + kk[j]] = pos;
      pos++;
    }
  }
  if (tid == 255) cnt[e] = woff + inc;
  if (tid == 0) ebase[e] = baseE;
}

// ---------------------------------------------------------------------------
// Fused SwiGLU GEMM: act = silu(A@Bg^T) * (A@Bu^T), bf16 in/out, fp32 acc.
// BN=64, BK=32. BM=128 (shared, waves 2x2 over 64x32 each) or BM=64
// (gathered experts, waves 2x2 over 32x32 each -> more blocks for TLP).
// LDS double-buffered: ONE barrier per K-iter; prefetch of iter i+1 issued
// right after the barrier so it overlaps the MFMA phase of iter i.
// ---------------------------------------------------------------------------
template <bool GATHER, int BM>
__global__ __launch_bounds__(256, (BM == 64 ? 4 : 2)) void swiglu_gemm(
    const unsigned short* __restrict__ A,   // [rows, K] bf16
    const unsigned short* __restrict__ Bg,  // gate weights [N,K] (+e*estrideB)
    const unsigned short* __restrict__ Bu,  // up weights   [N,K] (+e*estrideB)
    unsigned short* __restrict__ Out,       // [baseE+m, N] bf16
    const int* __restrict__ slot_token, const int* __restrict__ cnt,
    const int* __restrict__ ebase, int M, int N, int K, long estrideB) {
  const int BN = 64, BK = 32;
  const int MT = BM / 32;   // m-tiles (16 rows) per wave
  const int ACH = BM / 64;  // A 1KB chunks staged per wave
  const int tid = threadIdx.x;
  const int lane = tid & 63;
  const int wid = tid >> 6;
  const int wm = wid & 1;   // wave row
  const int wn = wid >> 1;  // wave col (32 cols)
  const int e = blockIdx.z;
  const int m0 = blockIdx.y * BM;
  const int n0 = blockIdx.x * BN;
  int Meff = M, baseE = 0;
  if (GATHER) {
    Meff = cnt[e];
    if (m0 >= Meff) return;
    baseE = ebase[e];
  }
  const unsigned short* BgE = Bg + (long)e * estrideB;
  const unsigned short* BuE = Bu + (long)e * estrideB;

  __shared__ __align__(16) unsigned short As[2][BM * BK];
  __shared__ __align__(16) unsigned short Bgs[2][BN * BK];
  __shared__ __align__(16) unsigned short Bus[2][BN * BK];

  const int lrow = lane >> 2;        // 16 rows / 1KB chunk
  const int lcol = (lane & 3) * 16;  // byte offset in 64B row

  const char* aP[ACH];
#pragma unroll
  for (int i = 0; i < ACH; ++i) {
    int m = m0 + wid * (16 * ACH) + i * 16 + lrow;
    long row;
    if (GATHER) {
      int mm = (m < Meff - 1) ? m : (Meff - 1);  // clamp tail to valid slot
      row = slot_token[baseE + mm];
    } else {
      row = m;
    }
    aP[i] = (const char*)A + row * (long)(K * 2) + lcol;
  }
  int nb = n0 + wid * 16 + lrow;
  const char* bgP = (const char*)BgE + (long)nb * (K * 2) + lcol;
  const char* buP = (const char*)BuE + (long)nb * (K * 2) + lcol;

  floatx4 accG[MT][2], accU[MT][2];
  floatx4 zero = {0.f, 0.f, 0.f, 0.f};
#pragma unroll
  for (int i = 0; i < MT; ++i)
#pragma unroll
    for (int j = 0; j < 2; ++j) { accG[i][j] = zero; accU[i][j] = zero; }

  const int ar = lane & 15;
  const int ak = (lane >> 4) * 8;

  auto stage = [&](int p, int k0) {
#pragma unroll
    for (int i = 0; i < ACH; ++i)
      gl_lds16(aP[i] + (long)k0 * 2, &As[p][(wid * 16 * ACH + i * 16) * BK]);
    gl_lds16(bgP + (long)k0 * 2, &Bgs[p][(wid * 16) * BK]);
    gl_lds16(buP + (long)k0 * 2, &Bus[p][(wid * 16) * BK]);
  };

  stage(0, 0);
  const int NI = K / BK;
  for (int i = 0; i < NI; ++i) {
    __syncthreads();  // compiler drains vmcnt before s_barrier -> buf[i&1] ready
    if (i + 1 < NI) stage((i + 1) & 1, (i + 1) * BK);
    const unsigned short* Ab = As[i & 1];
    const unsigned short* Gb = Bgs[i & 1];
    const unsigned short* Ub = Bus[i & 1];
    short8 af[MT], bgf[2], buf2[2];
#pragma unroll
    for (int tm = 0; tm < MT; ++tm)
      af[tm] = *(const short8*)&Ab[(wm * (BM / 2) + tm * 16 + ar) * BK + ak];
#pragma unroll
    for (int tn = 0; tn < 2; ++tn) {
      bgf[tn] = *(const short8*)&Gb[(wn * 32 + tn * 16 + ar) * BK + ak];
      buf2[tn] = *(const short8*)&Ub[(wn * 32 + tn * 16 + ar) * BK + ak];
    }
#pragma unroll
    for (int tm = 0; tm < MT; ++tm)
#pragma unroll
      for (int tn = 0; tn < 2; ++tn) {
        accG[tm][tn] = __builtin_amdgcn_mfma_f32_16x16x32_bf16(af[tm], bgf[tn], accG[tm][tn], 0, 0, 0);
        accU[tm][tn] = __builtin_amdgcn_mfma_f32_16x16x32_bf16(af[tm], buf2[tn], accU[tm][tn], 0, 0, 0);
      }
  }

#pragma unroll
  for (int tm = 0; tm < MT; ++tm)
#pragma unroll
    for (int tn = 0; tn < 2; ++tn)
#pragma unroll
      for (int r = 0; r < 4; ++r) {
        int row = m0 + wm * (BM / 2) + tm * 16 + (lane >> 4) * 4 + r;
        int col = n0 + wn * 32 + tn * 16 + (lane & 15);
        if (!GATHER || row < Meff) {
          float g = accG[tm][tn][r];
          float u = accU[tm][tn][r];
          float act = g / (1.f + expf(-g)) * u;
          Out[(long)(baseE + row) * N + col] = f2bf(act);
        }
      }
}

// ---------------------------------------------------------------------------
// Down-proj GEMM: C = A@B^T, BN=64, BK=32, double-buffered (1 barrier/iter).
// MODE 1 (expert, BM=64): plain bf16 store to compact eout[slot][h].
// MODE 0 (shared, BM=64): fused combine epilogue
//   out[t][h] = sg[t]*v + w0*eout[slot0(t)][h] + w1*eout[slot1(t)][h].
// ---------------------------------------------------------------------------
template <int MODE, int BM>
__global__ __launch_bounds__(256, (BM == 64 ? 4 : 2)) void down_gemm(
    const unsigned short* __restrict__ A,  // [rows, K] bf16 (compact for MODE1)
    const unsigned short* __restrict__ B,  // [N,K] bf16 (+e*estrideB)
    float* __restrict__ OutF,              // MODE0: [T, H] fp32
    unsigned short* __restrict__ OutB,     // MODE1: eout bf16 [4096, H]
    const float* __restrict__ sg, const float2* __restrict__ w01,
    const int* __restrict__ tok_slot, const unsigned short* __restrict__ eout,
    const int* __restrict__ ebase, const int* __restrict__ cnt,
    int M, int N, int K, long estrideB) {
  const int BN = 64, BK = 32;
  const int MT = BM / 32;
  const int ACH = BM / 64;
  const int tid = threadIdx.x;
  const int lane = tid & 63;
  const int wid = tid >> 6;
  const int wm = wid & 1;
  const int wn = wid >> 1;
  const int e = blockIdx.z;
  const int m0 = blockIdx.y * BM;
  const int n0 = blockIdx.x * BN;
  int Meff = M, baseE = 0;
  if (MODE == 1) {
    Meff = cnt[e];
    if (m0 >= Meff) return;
    baseE = ebase[e];
  }
  const unsigned short* BE = B + (long)e * estrideB;

  __shared__ __align__(16) unsigned short As[2][BM * BK];
  __shared__ __align__(16) unsigned short Bs[2][BN * BK];

  const int lrow = lane >> 2;
  const int lcol = (lane & 3) * 16;

  const char* aP[ACH];
#pragma unroll
  for (int i = 0; i < ACH; ++i) {
    int m = m0 + wid * (16 * ACH) + i * 16 + lrow;
    long arow;
    if (MODE == 1) {
      int mm = (m < Meff - 1) ? m : (Meff - 1);
      arow = baseE + mm;
    } else {
      arow = m;
    }
    aP[i] = (const char*)A + arow * (long)(K * 2) + lcol;
  }
  int nb = n0 + wid * 16 + lrow;
  const char* bP = (const char*)BE + (long)nb * (K * 2) + lcol;

  floatx4 acc[MT][2];
  floatx4 zero = {0.f, 0.f, 0.f, 0.f};
#pragma unroll
  for (int i = 0; i < MT; ++i)
#pragma unroll
    for (int j = 0; j < 2; ++j) acc[i][j] = zero;

  const int ar = lane & 15;
  const int ak = (lane >> 4) * 8;

  auto stage = [&](int p, int k0) {
#pragma unroll
    for (int i = 0; i < ACH; ++i)
      gl_lds16(aP[i] + (long)k0 * 2, &As[p][(wid * 16 * ACH + i * 16) * BK]);
    gl_lds16(bP + (long)k0 * 2, &Bs[p][(wid * 16) * BK]);
  };

  stage(0, 0);
  const int NI = K / BK;
  for (int i = 0; i < NI; ++i) {
    __syncthreads();
    if (i + 1 < NI) stage((i + 1) & 1, (i + 1) * BK);
    const unsigned short* Ab = As[i & 1];
    const unsigned short* Bb = Bs[i & 1];
    short8 af[MT], bf[2];
#pragma unroll
    for (int tm = 0; tm < MT; ++tm)
      af[tm] = *(const short8*)&Ab[(wm * (BM / 2) + tm * 16 + ar) * BK + ak];
#pragma unroll
    for (int tn = 0; tn < 2; ++tn)
      bf[tn] = *(const short8*)&Bb[(wn * 32 + tn * 16 + ar) * BK + ak];
#pragma unroll
    for (int tm = 0; tm < MT; ++tm)
#pragma unroll
      for (int tn = 0; tn < 2; ++tn)
        acc[tm][tn] = __builtin_amdgcn_mfma_f32_16x16x32_bf16(af[tm], bf[tn], acc[tm][tn], 0, 0, 0);
  }

#pragma unroll
  for (int tm = 0; tm < MT; ++tm)
#pragma unroll
    for (int r = 0; r < 4; ++r) {
      int row = m0 + wm * (BM / 2) + tm * 16 + (lane >> 4) * 4 + r;
      if (MODE == 0) {
        float sgr = sg[row];
        float2 wr = w01[row];
        int s0 = tok_slot[2 * row];
        int s1 = tok_slot[2 * row + 1];
#pragma unroll
        for (int tn = 0; tn < 2; ++tn) {
          int col = n0 + wn * 32 + tn * 16 + (lane & 15);
          float v = acc[tm][tn][r];
          float ev0 = bf2f(eout[(long)s0 * N + col]);
          float ev1 = bf2f(eout[(long)s1 * N + col]);
          OutF[(long)row * N + col] = sgr * v + wr.x * ev0 + wr.y * ev1;
        }
      } else {
        if (row < Meff) {
#pragma unroll
          for (int tn = 0; tn < 2; ++tn) {
            int col = n0 + wn * 32 + tn * 16 + (lane & 15);
            OutB[(long)(baseE + row) * N + col] = f2bf(acc[tm][tn][r]);
          }
        }
      }
    }
}

// ---------------------------------------------------------------------------
// Workspace map (bytes): same as round 3, total ~63.0 MB
// ---------------------------------------------------------------------------
extern "C" void kernel_launch(void* const* d_in, const int* in_sizes, int n_in,
                              void* d_out, int out_size, void* d_ws, size_t ws_size,
                              hipStream_t stream) {
  const float* x = (const float*)d_in[0];
  const float* rw = (const float*)d_in[1];
  const float* gup = (const float*)d_in[2];
  const float* dwn = (const float*)d_in[3];
  const float* sgw = (const float*)d_in[4];
  const float* suw = (const float*)d_in[5];
  const float* sdw = (const float*)d_in[6];
  const float* segw = (const float*)d_in[7];
  float* out = (float*)d_out;

  char* w = (char*)d_ws;
  unsigned short* xb = (unsigned short*)(w + 0);
  unsigned short* gup_b = (unsigned short*)(w + 4194304L);
  unsigned short* down_b = (unsigned short*)(w + 20971520L);
  unsigned short* sgate_b = (unsigned short*)(w + 29360128L);
  unsigned short* sup_b = (unsigned short*)(w + 33554432L);
  unsigned short* sdown_b = (unsigned short*)(w + 37748736L);
  unsigned short* act_s = (unsigned short*)(w + 41943040L);
  unsigned short* act_e = (unsigned short*)(w + 50331648L);
  unsigned short* eout = (unsigned short*)(w + 54525952L);
  float* sg = (float*)(w + 62914560L);
  int* top2 = (int*)(w + 62922752L);
  float2* w01 = (float2*)(w + 62930944L);
  int* cnt = (int*)(w + 62947328L);
  int* ebase = (int*)(w + 62947584L);
  int* slot_token = (int*)(w + 62947840L);
  int* tok_slot = (int*)(w + 62964224L);

  cast_all<<<20480, 256, 0, stream>>>(x, gup, dwn, sgw, suw, sdw, xb, gup_b,
                                      down_b, sgate_b, sup_b, sdown_b);
  router_kernel<<<512, 256, 0, stream>>>(x, rw, segw, top2, w01, sg);
  build_lists<<<E_NUM, 256, 0, stream>>>(top2, cnt, ebase, slot_token, tok_slot);
  // shared SwiGLU: [2048,1024] x [2048,1024]^T (gate & up) -> act_s [2048,2048]
  swiglu_gemm<false, 128><<<dim3(32, 16, 1), 256, 0, stream>>>(
      xb, sgate_b, sup_b, act_s, nullptr, nullptr, nullptr, 2048, SI_DIM, H_DIM, 0);
  // expert SwiGLU: gathered tokens x gate_up_proj[e] -> act_e [slot, 512] compact
  swiglu_gemm<true, 64><<<dim3(8, 32, 8), 256, 0, stream>>>(
      xb, gup_b, gup_b + (long)I_DIM * H_DIM, act_e, slot_token, cnt, ebase,
      T_TOK, I_DIM, H_DIM, (long)2 * I_DIM * H_DIM);
  // expert down: act_e x down_proj[e]^T -> eout[slot][h] (plain bf16 store)
  down_gemm<1, 64><<<dim3(16, 32, 8), 256, 0, stream>>>(
      act_e, down_b, nullptr, eout, nullptr, nullptr, nullptr, nullptr, ebase,
      cnt, T_TOK, H_DIM, I_DIM, (long)H_DIM * I_DIM);
  // shared down + combine: act_s x sdown^T; out = sg*v + w0*eout[s0] + w1*eout[s1]
  down_gemm<0, 64><<<dim3(16, 32, 1), 256, 0, stream>>>(
      act_s, sdown_b, out, nullptr, sg, w01, tok_slot, eout, nullptr, nullptr,
      T_TOK, H_DIM, SI_DIM, 0);
}

// Round 5
// 217.973 us; speedup vs baseline: 1.5580x; 1.1434x over previous
//
#include <hip/hip_runtime.h>

// Problem constants (B=2,S=1024 -> T=2048; H=1024, I=512, SI=2048, E=8, TOPK=2)
#define T_TOK 2048
#define H_DIM 1024
#define I_DIM 512
#define SI_DIM 2048
#define E_NUM 8
#define NSLOT 4096  // total expert slots: exactly 2 per token

typedef __attribute__((ext_vector_type(8))) short short8;   // 8 x bf16 (4 VGPRs)
typedef __attribute__((ext_vector_type(4))) float floatx4;  // MFMA C/D

// fp32 -> bf16 round-to-nearest-even
__device__ inline unsigned short f2bf(float f) {
  unsigned u = __builtin_bit_cast(unsigned, f);
  u = (u + 0x7FFFu + ((u >> 16) & 1u)) >> 16;
  return (unsigned short)u;
}
__device__ inline float bf2f(unsigned short u) {
  return __builtin_bit_cast(float, (unsigned)u << 16);
}

// async global->LDS, 16B per lane; LDS dest = wave-uniform base + lane*16
__device__ inline void gl_lds16(const void* g, void* l) {
  __builtin_amdgcn_global_load_lds(
      (const __attribute__((address_space(1))) unsigned int*)g,
      (__attribute__((address_space(3))) unsigned int*)l, 16, 0, 0);
}

// ---------------------------------------------------------------------------
// Cast all fp32 inputs needed in bf16 form. 6 segments, 4 elems/thread.
// ---------------------------------------------------------------------------
__global__ void cast_all(const float* __restrict__ s0, const float* __restrict__ s1,
                         const float* __restrict__ s2, const float* __restrict__ s3,
                         const float* __restrict__ s4, const float* __restrict__ s5,
                         unsigned short* __restrict__ d0, unsigned short* __restrict__ d1,
                         unsigned short* __restrict__ d2, unsigned short* __restrict__ d3,
                         unsigned short* __restrict__ d4, unsigned short* __restrict__ d5) {
  long g = (long)blockIdx.x * blockDim.x + threadIdx.x;  // group of 4 elems
  const float* s;
  unsigned short* d;
  long off;
  if (g < 524288L)       { s = s0; d = d0; off = g; }            // x
  else if (g < 2621440L) { s = s1; d = d1; off = g - 524288L; }  // gate_up
  else if (g < 3670016L) { s = s2; d = d2; off = g - 2621440L; } // down
  else if (g < 4194304L) { s = s3; d = d3; off = g - 3670016L; } // shared_gate
  else if (g < 4718592L) { s = s4; d = d4; off = g - 4194304L; } // shared_up
  else                   { s = s5; d = d5; off = g - 4718592L; } // shared_down
  float4 v = ((const float4*)s)[off];
  ushort4 o;
  o.x = f2bf(v.x); o.y = f2bf(v.y); o.z = f2bf(v.z); o.w = f2bf(v.w);
  ((ushort4*)d)[off] = o;
}

// ---------------------------------------------------------------------------
// Router phase 1: one wave per token, fp32 logits, top-2 lowest-index
// tie-break, renormalized weights, sigmoid shared gate. No atomics.
// ---------------------------------------------------------------------------
__global__ void router_kernel(const float* __restrict__ x,
                              const float* __restrict__ rw,
                              const float* __restrict__ segw,
                              int* __restrict__ top2,
                              float2* __restrict__ w01,
                              float* __restrict__ sg) {
  int t = blockIdx.x * 4 + (threadIdx.x >> 6);
  int lane = threadIdx.x & 63;
  const float* xt = x + (long)t * H_DIM;
  float xv[16];
#pragma unroll
  for (int j = 0; j < 16; ++j) xv[j] = xt[j * 64 + lane];
  float dots[9];
#pragma unroll
  for (int e = 0; e < 8; ++e) {
    const float* w = rw + e * H_DIM;
    float s = 0.f;
#pragma unroll
    for (int j = 0; j < 16; ++j) s += xv[j] * w[j * 64 + lane];
    dots[e] = s;
  }
  {
    float s = 0.f;
#pragma unroll
    for (int j = 0; j < 16; ++j) s += xv[j] * segw[j * 64 + lane];
    dots[8] = s;
  }
#pragma unroll
  for (int off = 32; off > 0; off >>= 1) {
#pragma unroll
    for (int e = 0; e < 9; ++e) dots[e] += __shfl_xor(dots[e], off, 64);
  }
  if (lane == 0) {
    int e0 = 0;
    for (int e = 1; e < 8; ++e)
      if (dots[e] > dots[e0]) e0 = e;
    int e1 = (e0 == 0) ? 1 : 0;
    for (int e = 0; e < 8; ++e)
      if (e != e0 && dots[e] > dots[e1]) e1 = e;
    float p1 = expf(dots[e1] - dots[e0]);
    float w0 = 1.f / (1.f + p1);
    float w1 = p1 / (1.f + p1);
    top2[t] = e0 | (e1 << 8);
    w01[t] = make_float2(w0, w1);
    sg[t] = 1.f / (1.f + expf(-dots[8]));
  }
}

// ---------------------------------------------------------------------------
// Router phase 2: one block per expert; block-wide scan -> compact slot list
// (global base = #assignments to experts < e) + tok_slot back-pointers.
// ---------------------------------------------------------------------------
__global__ __launch_bounds__(256) void build_lists(
    const int* __restrict__ top2, int* __restrict__ cnt, int* __restrict__ ebase,
    int* __restrict__ slot_token, int* __restrict__ tok_slot) {
  const int e = blockIdx.x;
  const int tid = threadIdx.x;
  const int lane = tid & 63, wid = tid >> 6;
  __shared__ int wsum[4], wbelow[4];
  const int base_t = tid * 8;  // 2048 / 256
  int mk[8], kk[8];
  int c = 0, below = 0;
#pragma unroll
  for (int j = 0; j < 8; ++j) {
    int p = top2[base_t + j];
    int e0 = p & 0xFF, e1 = (p >> 8) & 0xFF;
    below += (e0 < e) + (e1 < e);
    int m = 0, k = 0;
    if (e0 == e) { m = 1; k = 0; }
    else if (e1 == e) { m = 1; k = 1; }
    mk[j] = m; kk[j] = k;
    c += m;
  }
  int inc = c;
#pragma unroll
  for (int off = 1; off < 64; off <<= 1) {
    int n = __shfl_up(inc, off, 64);
    if (lane >= off) inc += n;
  }
  int bsum = below;
#pragma unroll
  for (int off = 32; off > 0; off >>= 1) bsum += __shfl_xor(bsum, off, 64);
  if (lane == 63) wsum[wid] = inc;
  if (lane == 0) wbelow[wid] = bsum;
  __syncthreads();
  int woff = 0;
#pragma unroll
  for (int i = 0; i < 4; ++i)
    if (i < wid) woff += wsum[i];
  int baseE = wbelow[0] + wbelow[1] + wbelow[2] + wbelow[3];
  int pos = baseE + woff + inc - c;
#pragma unroll
  for (int j = 0; j < 8; ++j) {
    if (mk[j]) {
      slot_token[pos] = base_t + j;
      tok_slot[2 * (base_t + j) + kk[j]] = pos;
      pos++;
    }
  }
  if (tid == 255) cnt[e] = woff + inc;
  if (tid == 0) ebase[e] = baseE;
}

// ---------------------------------------------------------------------------
// Fused SwiGLU GEMM body: act = silu(A@Bg^T)*(A@Bu^T), bf16, fp32 acc.
// BN=64, BK=32, double-buffered LDS (1 barrier/iter), XOR bank swizzle:
//   stage: lane fetches global 16B-chunk (lane&3)^((lrow>>1)&3) of its row
//   read : row ar, k-chunk kq lives at LDS chunk kq^((ar>>1)&3)
// ---------------------------------------------------------------------------
template <bool GATHER, int BM>
__device__ __forceinline__ void swiglu_body(
    char* smem, int bx, int by, int e,
    const unsigned short* __restrict__ A, const unsigned short* __restrict__ Bg,
    const unsigned short* __restrict__ Bu, unsigned short* __restrict__ Out,
    const int* __restrict__ slot_token, const int* __restrict__ cnt,
    const int* __restrict__ ebase, int N, int K, long estrideB) {
  const int BK = 32;
  const int MT = BM / 32;   // m-tiles per wave
  const int ACH = BM / 64;  // A 1KB chunks staged per wave
  const int tid = threadIdx.x;
  const int lane = tid & 63;
  const int wid = tid >> 6;
  const int wm = wid & 1;
  const int wn = wid >> 1;
  const int m0 = by * BM;
  const int n0 = bx * 64;
  int Meff = 0, baseE = 0;
  if (GATHER) {
    Meff = cnt[e];
    if (m0 >= Meff) return;
    baseE = ebase[e];
  }
  const unsigned short* BgE = Bg + (long)e * estrideB;
  const unsigned short* BuE = Bu + (long)e * estrideB;

  unsigned short* As = (unsigned short*)smem;          // [2][BM*BK]
  unsigned short* Bgs = As + 2 * BM * BK;              // [2][64*BK]
  unsigned short* Bus = Bgs + 2 * 64 * BK;             // [2][64*BK]

  const int lrow = lane >> 2;  // 16 rows / 1KB chunk
  // swizzled byte offset within the 64B row (stage side)
  const int lcol = (((lane & 3) ^ ((lrow >> 1) & 3)) << 4);

  const char* aP[ACH];
#pragma unroll
  for (int i = 0; i < ACH; ++i) {
    int m = m0 + wid * (16 * ACH) + i * 16 + lrow;
    long row;
    if (GATHER) {
      int mm = (m < Meff - 1) ? m : (Meff - 1);  // clamp tail to valid slot
      row = slot_token[baseE + mm];
    } else {
      row = m;
    }
    aP[i] = (const char*)A + row * (long)(K * 2) + lcol;
  }
  int nb = n0 + wid * 16 + lrow;
  const char* bgP = (const char*)BgE + (long)nb * (K * 2) + lcol;
  const char* buP = (const char*)BuE + (long)nb * (K * 2) + lcol;

  floatx4 accG[MT][2], accU[MT][2];
  floatx4 zero = {0.f, 0.f, 0.f, 0.f};
#pragma unroll
  for (int i = 0; i < MT; ++i)
#pragma unroll
    for (int j = 0; j < 2; ++j) { accG[i][j] = zero; accU[i][j] = zero; }

  const int ar = lane & 15;
  // swizzled k-offset (ushorts) for fragment reads — per-thread constant
  const int aksw = (((lane >> 4) ^ ((ar >> 1) & 3)) << 3);

  auto stage = [&](int p, int k0) {
#pragma unroll
    for (int i = 0; i < ACH; ++i)
      gl_lds16(aP[i] + (long)k0 * 2, &As[p * BM * BK + (wid * 16 * ACH + i * 16) * BK]);
    gl_lds16(bgP + (long)k0 * 2, &Bgs[p * 64 * BK + (wid * 16) * BK]);
    gl_lds16(buP + (long)k0 * 2, &Bus[p * 64 * BK + (wid * 16) * BK]);
  };

  stage(0, 0);
  const int NI = K / BK;
  for (int i = 0; i < NI; ++i) {
    __syncthreads();
    if (i + 1 < NI) stage((i + 1) & 1, (i + 1) * BK);
    const unsigned short* Ab = &As[(i & 1) * BM * BK];
    const unsigned short* Gb = &Bgs[(i & 1) * 64 * BK];
    const unsigned short* Ub = &Bus[(i & 1) * 64 * BK];
    short8 af[MT], bgf[2], buf2[2];
#pragma unroll
    for (int tm = 0; tm < MT; ++tm)
      af[tm] = *(const short8*)&Ab[(wm * (BM / 2) + tm * 16 + ar) * BK + aksw];
#pragma unroll
    for (int tn = 0; tn < 2; ++tn) {
      bgf[tn] = *(const short8*)&Gb[(wn * 32 + tn * 16 + ar) * BK + aksw];
      buf2[tn] = *(const short8*)&Ub[(wn * 32 + tn * 16 + ar) * BK + aksw];
    }
#pragma unroll
    for (int tm = 0; tm < MT; ++tm)
#pragma unroll
      for (int tn = 0; tn < 2; ++tn) {
        accG[tm][tn] = __builtin_amdgcn_mfma_f32_16x16x32_bf16(af[tm], bgf[tn], accG[tm][tn], 0, 0, 0);
        accU[tm][tn] = __builtin_amdgcn_mfma_f32_16x16x32_bf16(af[tm], buf2[tn], accU[tm][tn], 0, 0, 0);
      }
  }

#pragma unroll
  for (int tm = 0; tm < MT; ++tm)
#pragma unroll
    for (int tn = 0; tn < 2; ++tn)
#pragma unroll
      for (int r = 0; r < 4; ++r) {
        int row = m0 + wm * (BM / 2) + tm * 16 + (lane >> 4) * 4 + r;
        int col = n0 + wn * 32 + tn * 16 + (lane & 15);
        if (!GATHER || row < Meff) {
          float g = accG[tm][tn][r];
          float u = accU[tm][tn][r];
          float act = g / (1.f + expf(-g)) * u;
          Out[(long)(baseE + row) * N + col] = f2bf(act);
        }
      }
}

// Fused launch: blocks [0,512) = shared SwiGLU (BM=128, M=2048,N=2048,K=1024);
// blocks [512,2560) = expert SwiGLU (BM=64, gathered, N=512,K=1024).
__global__ __launch_bounds__(256, 2) void swiglu_fused(
    const unsigned short* __restrict__ xb, const unsigned short* __restrict__ sgate,
    const unsigned short* __restrict__ sup, unsigned short* __restrict__ act_s,
    const unsigned short* __restrict__ gup, unsigned short* __restrict__ act_e,
    const int* __restrict__ slot_token, const int* __restrict__ cnt,
    const int* __restrict__ ebase) {
  __shared__ __align__(16) char smem[32768];
  int bid = blockIdx.x;
  if (bid < 512) {
    // by in [0,16), bx in [0,32)
    swiglu_body<false, 128>(smem, bid & 31, bid >> 5, 0, xb, sgate, sup, act_s,
                            nullptr, nullptr, nullptr, SI_DIM, H_DIM, 0);
  } else {
    int b2 = bid - 512;
    int e = b2 >> 8;
    int rem = b2 & 255;  // by in [0,32), bx in [0,8)
    swiglu_body<true, 64>(smem, rem & 7, rem >> 3, e, xb, gup,
                          gup + (long)I_DIM * H_DIM, act_e, slot_token, cnt,
                          ebase, I_DIM, H_DIM, (long)2 * I_DIM * H_DIM);
  }
}

// ---------------------------------------------------------------------------
// Down-proj GEMM body: C = A@B^T, BM=64, BN=64, BK=32, dbuf + swizzle.
// MODE 0 (shared): OutF[row][col] = sg[row]*v   (plain fp32 store)
// MODE 1 (expert): OutB[(baseE+row)][col] = bf16(v)
// ---------------------------------------------------------------------------
template <int MODE>
__device__ __forceinline__ void down_body(
    char* smem, int bx, int by, int e,
    const unsigned short* __restrict__ A, const unsigned short* __restrict__ B,
    float* __restrict__ OutF, unsigned short* __restrict__ OutB,
    const float* __restrict__ sg, const int* __restrict__ ebase,
    const int* __restrict__ cnt, int N, int K, long estrideB) {
  const int BM = 64, BK = 32;
  const int tid = threadIdx.x;
  const int lane = tid & 63;
  const int wid = tid >> 6;
  const int wm = wid & 1;
  const int wn = wid >> 1;
  const int m0 = by * BM;
  const int n0 = bx * 64;
  int Meff = 0, baseE = 0;
  if (MODE == 1) {
    Meff = cnt[e];
    if (m0 >= Meff) return;
    baseE = ebase[e];
  }
  const unsigned short* BE = B + (long)e * estrideB;

  unsigned short* As = (unsigned short*)smem;   // [2][64*BK]
  unsigned short* Bs = As + 2 * 64 * BK;        // [2][64*BK]

  const int lrow = lane >> 2;
  const int lcol = (((lane & 3) ^ ((lrow >> 1) & 3)) << 4);

  int m = m0 + wid * 16 + lrow;
  long arow;
  if (MODE == 1) {
    int mm = (m < Meff - 1) ? m : (Meff - 1);
    arow = baseE + mm;
  } else {
    arow = m;
  }
  const char* aP = (const char*)A + arow * (long)(K * 2) + lcol;
  int nb = n0 + wid * 16 + lrow;
  const char* bP = (const char*)BE + (long)nb * (K * 2) + lcol;

  floatx4 acc[2][2];
  floatx4 zero = {0.f, 0.f, 0.f, 0.f};
#pragma unroll
  for (int i = 0; i < 2; ++i)
#pragma unroll
    for (int j = 0; j < 2; ++j) acc[i][j] = zero;

  const int ar = lane & 15;
  const int aksw = (((lane >> 4) ^ ((ar >> 1) & 3)) << 3);

  auto stage = [&](int p, int k0) {
    gl_lds16(aP + (long)k0 * 2, &As[p * 64 * BK + (wid * 16) * BK]);
    gl_lds16(bP + (long)k0 * 2, &Bs[p * 64 * BK + (wid * 16) * BK]);
  };

  stage(0, 0);
  const int NI = K / BK;
  for (int i = 0; i < NI; ++i) {
    __syncthreads();
    if (i + 1 < NI) stage((i + 1) & 1, (i + 1) * BK);
    const unsigned short* Ab = &As[(i & 1) * 64 * BK];
    const unsigned short* Bb = &Bs[(i & 1) * 64 * BK];
    short8 af[2], bf[2];
#pragma unroll
    for (int tm = 0; tm < 2; ++tm)
      af[tm] = *(const short8*)&Ab[(wm * 32 + tm * 16 + ar) * BK + aksw];
#pragma unroll
    for (int tn = 0; tn < 2; ++tn)
      bf[tn] = *(const short8*)&Bb[(wn * 32 + tn * 16 + ar) * BK + aksw];
#pragma unroll
    for (int tm = 0; tm < 2; ++tm)
#pragma unroll
      for (int tn = 0; tn < 2; ++tn)
        acc[tm][tn] = __builtin_amdgcn_mfma_f32_16x16x32_bf16(af[tm], bf[tn], acc[tm][tn], 0, 0, 0);
  }

#pragma unroll
  for (int tm = 0; tm < 2; ++tm)
#pragma unroll
    for (int r = 0; r < 4; ++r) {
      int row = m0 + wm * 32 + tm * 16 + (lane >> 4) * 4 + r;
#pragma unroll
      for (int tn = 0; tn < 2; ++tn) {
        int col = n0 + wn * 32 + tn * 16 + (lane & 15);
        float v = acc[tm][tn][r];
        if (MODE == 0) {
          OutF[(long)row * N + col] = sg[row] * v;
        } else if (row < Meff) {
          OutB[(long)(baseE + row) * N + col] = f2bf(v);
        }
      }
    }
}

// Fused launch: blocks [0,512) = shared down (M=2048,N=1024,K=2048);
// blocks [512,4608) = expert down (per-expert, N=1024,K=512).
__global__ __launch_bounds__(256, 4) void down_fused(
    const unsigned short* __restrict__ act_s, const unsigned short* __restrict__ sdown,
    float* __restrict__ out, const float* __restrict__ sg,
    const unsigned short* __restrict__ act_e, const unsigned short* __restrict__ downw,
    unsigned short* __restrict__ eout, const int* __restrict__ ebase,
    const int* __restrict__ cnt) {
  __shared__ __align__(16) char smem[16384];
  int bid = blockIdx.x;
  if (bid < 512) {
    // by in [0,32), bx in [0,16)
    down_body<0>(smem, bid & 15, bid >> 4, 0, act_s, sdown, out, nullptr, sg,
                 nullptr, nullptr, H_DIM, SI_DIM, 0);
  } else {
    int b2 = bid - 512;
    int e = b2 >> 9;
    int rem = b2 & 511;  // by in [0,32), bx in [0,16)
    down_body<1>(smem, rem & 15, rem >> 4, e, act_e, downw, nullptr, eout,
                 nullptr, ebase, cnt, H_DIM, I_DIM, (long)H_DIM * I_DIM);
  }
}

// ---------------------------------------------------------------------------
// Combine: out[t][h] += w0*eout[s0][h] + w1*eout[s1][h]. One block per token.
// ---------------------------------------------------------------------------
__global__ __launch_bounds__(256) void combine_kernel(
    float* __restrict__ out, const unsigned short* __restrict__ eout,
    const float2* __restrict__ w01, const int* __restrict__ tok_slot) {
  int t = blockIdx.x;
  int c = threadIdx.x;  // 256 threads x 4 elems = 1024
  float2 wr = w01[t];
  int s0 = tok_slot[2 * t];
  int s1 = tok_slot[2 * t + 1];
  ushort4 e0 = ((const ushort4*)(eout + (long)s0 * H_DIM))[c];
  ushort4 e1 = ((const ushort4*)(eout + (long)s1 * H_DIM))[c];
  float4* op = &((float4*)(out + (long)t * H_DIM))[c];
  float4 o = *op;
  o.x += wr.x * bf2f(e0.x) + wr.y * bf2f(e1.x);
  o.y += wr.x * bf2f(e0.y) + wr.y * bf2f(e1.y);
  o.z += wr.x * bf2f(e0.z) + wr.y * bf2f(e1.z);
  o.w += wr.x * bf2f(e0.w) + wr.y * bf2f(e1.w);
  *op = o;
}

// ---------------------------------------------------------------------------
// Workspace map (bytes): same as round 3/4, total ~63.0 MB
// ---------------------------------------------------------------------------
extern "C" void kernel_launch(void* const* d_in, const int* in_sizes, int n_in,
                              void* d_out, int out_size, void* d_ws, size_t ws_size,
                              hipStream_t stream) {
  const float* x = (const float*)d_in[0];
  const float* rw = (const float*)d_in[1];
  const float* gup = (const float*)d_in[2];
  const float* dwn = (const float*)d_in[3];
  const float* sgw = (const float*)d_in[4];
  const float* suw = (const float*)d_in[5];
  const float* sdw = (const float*)d_in[6];
  const float* segw = (const float*)d_in[7];
  float* out = (float*)d_out;

  char* w = (char*)d_ws;
  unsigned short* xb = (unsigned short*)(w + 0);
  unsigned short* gup_b = (unsigned short*)(w + 4194304L);
  unsigned short* down_b = (unsigned short*)(w + 20971520L);
  unsigned short* sgate_b = (unsigned short*)(w + 29360128L);
  unsigned short* sup_b = (unsigned short*)(w + 33554432L);
  unsigned short* sdown_b = (unsigned short*)(w + 37748736L);
  unsigned short* act_s = (unsigned short*)(w + 41943040L);
  unsigned short* act_e = (unsigned short*)(w + 50331648L);
  unsigned short* eout = (unsigned short*)(w + 54525952L);
  float* sg = (float*)(w + 62914560L);
  int* top2 = (int*)(w + 62922752L);
  float2* w01 = (float2*)(w + 62930944L);
  int* cnt = (int*)(w + 62947328L);
  int* ebase = (int*)(w + 62947584L);
  int* slot_token = (int*)(w + 62947840L);
  int* tok_slot = (int*)(w + 62964224L);

  cast_all<<<20480, 256, 0, stream>>>(x, gup, dwn, sgw, suw, sdw, xb, gup_b,
                                      down_b, sgate_b, sup_b, sdown_b);
  router_kernel<<<512, 256, 0, stream>>>(x, rw, segw, top2, w01, sg);
  build_lists<<<E_NUM, 256, 0, stream>>>(top2, cnt, ebase, slot_token, tok_slot);
  // fused shared+expert SwiGLU (independent; one launch for TLP)
  swiglu_fused<<<2560, 256, 0, stream>>>(xb, sgate_b, sup_b, act_s, gup_b,
                                         act_e, slot_token, cnt, ebase);
  // fused shared+expert down-proj (out = sg*v; eout = expert vals)
  down_fused<<<4608, 256, 0, stream>>>(act_s, sdown_b, out, sg, act_e, down_b,
                                       eout, ebase, cnt);
  // out += w0*eout[s0] + w1*eout[s1]
  combine_kernel<<<T_TOK, 256, 0, stream>>>(out, eout, w01, tok_slot);
}

// Round 6
// 208.383 us; speedup vs baseline: 1.6297x; 1.0460x over previous
//
#include <hip/hip_runtime.h>

// Problem constants (B=2,S=1024 -> T=2048; H=1024, I=512, SI=2048, E=8, TOPK=2)
#define T_TOK 2048
#define H_DIM 1024
#define I_DIM 512
#define SI_DIM 2048
#define E_NUM 8
#define NSLOT 4096  // total expert slots: exactly 2 per token

typedef __attribute__((ext_vector_type(8))) short short8;   // 8 x bf16 (4 VGPRs)
typedef __attribute__((ext_vector_type(4))) float floatx4;  // MFMA C/D

// fp32 -> bf16 round-to-nearest-even
__device__ inline unsigned short f2bf(float f) {
  unsigned u = __builtin_bit_cast(unsigned, f);
  u = (u + 0x7FFFu + ((u >> 16) & 1u)) >> 16;
  return (unsigned short)u;
}
__device__ inline float bf2f(unsigned short u) {
  return __builtin_bit_cast(float, (unsigned)u << 16);
}

// async global->LDS, 16B per lane; LDS dest = wave-uniform base + lane*16
__device__ inline void gl_lds16(const void* g, void* l) {
  __builtin_amdgcn_global_load_lds(
      (const __attribute__((address_space(1))) unsigned int*)g,
      (__attribute__((address_space(3))) unsigned int*)l, 16, 0, 0);
}

// ---------------------------------------------------------------------------
// Fused cast + router. Blocks [0,512): router (latency-bound, dispatched
// first so it overlaps the BW-bound cast flood). Blocks [512,20992): cast.
// ---------------------------------------------------------------------------
__global__ __launch_bounds__(256) void cast_router(
    const float* __restrict__ x, const float* __restrict__ rw,
    const float* __restrict__ segw,
    const float* __restrict__ s1, const float* __restrict__ s2,
    const float* __restrict__ s3, const float* __restrict__ s4,
    const float* __restrict__ s5,
    unsigned short* __restrict__ d0, unsigned short* __restrict__ d1,
    unsigned short* __restrict__ d2, unsigned short* __restrict__ d3,
    unsigned short* __restrict__ d4, unsigned short* __restrict__ d5,
    int* __restrict__ top2, float2* __restrict__ w01, float* __restrict__ sg) {
  const int bid = blockIdx.x;
  if (bid < 512) {
    // ---- router: one wave per token, fp32 logits (matches ref numerics) ----
    int t = bid * 4 + (threadIdx.x >> 6);
    int lane = threadIdx.x & 63;
    const float* xt = x + (long)t * H_DIM;
    float xv[16];
#pragma unroll
    for (int j = 0; j < 16; ++j) xv[j] = xt[j * 64 + lane];
    float dots[9];
#pragma unroll
    for (int e = 0; e < 8; ++e) {
      const float* w = rw + e * H_DIM;
      float s = 0.f;
#pragma unroll
      for (int j = 0; j < 16; ++j) s += xv[j] * w[j * 64 + lane];
      dots[e] = s;
    }
    {
      float s = 0.f;
#pragma unroll
      for (int j = 0; j < 16; ++j) s += xv[j] * segw[j * 64 + lane];
      dots[8] = s;
    }
#pragma unroll
    for (int off = 32; off > 0; off >>= 1) {
#pragma unroll
      for (int e = 0; e < 9; ++e) dots[e] += __shfl_xor(dots[e], off, 64);
    }
    if (lane == 0) {
      int e0 = 0;
      for (int e = 1; e < 8; ++e)
        if (dots[e] > dots[e0]) e0 = e;
      int e1 = (e0 == 0) ? 1 : 0;
      for (int e = 0; e < 8; ++e)
        if (e != e0 && dots[e] > dots[e1]) e1 = e;
      float p1 = expf(dots[e1] - dots[e0]);
      top2[t] = e0 | (e1 << 8);
      w01[t] = make_float2(1.f / (1.f + p1), p1 / (1.f + p1));
      sg[t] = 1.f / (1.f + expf(-dots[8]));
    }
  } else {
    // ---- cast: 6 fp32 segments -> bf16, 4 elems/thread ----
    long g = (long)(bid - 512) * 256 + threadIdx.x;
    const float* s;
    unsigned short* d;
    long off;
    if (g < 524288L)       { s = x;  d = d0; off = g; }            // x
    else if (g < 2621440L) { s = s1; d = d1; off = g - 524288L; }  // gate_up
    else if (g < 3670016L) { s = s2; d = d2; off = g - 2621440L; } // down
    else if (g < 4194304L) { s = s3; d = d3; off = g - 3670016L; } // shared_gate
    else if (g < 4718592L) { s = s4; d = d4; off = g - 4194304L; } // shared_up
    else                   { s = s5; d = d5; off = g - 4718592L; } // shared_down
    float4 v = ((const float4*)s)[off];
    ushort4 o;
    o.x = f2bf(v.x); o.y = f2bf(v.y); o.z = f2bf(v.z); o.w = f2bf(v.w);
    ((ushort4*)d)[off] = o;
  }
}

// ---------------------------------------------------------------------------
// Router phase 2: one block per expert; block-wide scan -> compact slot list
// (global base = #assignments to experts < e) + tok_slot back-pointers.
// ---------------------------------------------------------------------------
__global__ __launch_bounds__(256) void build_lists(
    const int* __restrict__ top2, int* __restrict__ cnt, int* __restrict__ ebase,
    int* __restrict__ slot_token, int* __restrict__ tok_slot) {
  const int e = blockIdx.x;
  const int tid = threadIdx.x;
  const int lane = tid & 63, wid = tid >> 6;
  __shared__ int wsum[4], wbelow[4];
  const int base_t = tid * 8;  // 2048 / 256
  int mk[8], kk[8];
  int c = 0, below = 0;
#pragma unroll
  for (int j = 0; j < 8; ++j) {
    int p = top2[base_t + j];
    int e0 = p & 0xFF, e1 = (p >> 8) & 0xFF;
    below += (e0 < e) + (e1 < e);
    int m = 0, k = 0;
    if (e0 == e) { m = 1; k = 0; }
    else if (e1 == e) { m = 1; k = 1; }
    mk[j] = m; kk[j] = k;
    c += m;
  }
  int inc = c;
#pragma unroll
  for (int off = 1; off < 64; off <<= 1) {
    int n = __shfl_up(inc, off, 64);
    if (lane >= off) inc += n;
  }
  int bsum = below;
#pragma unroll
  for (int off = 32; off > 0; off >>= 1) bsum += __shfl_xor(bsum, off, 64);
  if (lane == 63) wsum[wid] = inc;
  if (lane == 0) wbelow[wid] = bsum;
  __syncthreads();
  int woff = 0;
#pragma unroll
  for (int i = 0; i < 4; ++i)
    if (i < wid) woff += wsum[i];
  int baseE = wbelow[0] + wbelow[1] + wbelow[2] + wbelow[3];
  int pos = baseE + woff + inc - c;
#pragma unroll
  for (int j = 0; j < 8; ++j) {
    if (mk[j]) {
      slot_token[pos] = base_t + j;
      tok_slot[2 * (base_t + j) + kk[j]] = pos;
      pos++;
    }
  }
  if (tid == 255) cnt[e] = woff + inc;
  if (tid == 0) ebase[e] = baseE;
}

// ---------------------------------------------------------------------------
// Fused SwiGLU GEMM body: act = silu(A@Bg^T)*(A@Bu^T), bf16, fp32 acc.
// BM=128, BN=64, BK=32. 4 waves (2x2): each 64 rows x 32 cols, G+U.
// Per iter per wave: 8 ds_read_b128 feeding 16 MFMA (ratio 2.0).
// Double-buffered LDS (1 barrier/iter) + XOR bank swizzle (0 conflicts).
// ---------------------------------------------------------------------------
template <bool GATHER>
__device__ __forceinline__ void swiglu_body(
    char* smem, int bx, int by, int e,
    const unsigned short* __restrict__ A, const unsigned short* __restrict__ Bg,
    const unsigned short* __restrict__ Bu, unsigned short* __restrict__ Out,
    const int* __restrict__ slot_token, const int* __restrict__ cnt,
    const int* __restrict__ ebase, int N, int K, long estrideB) {
  const int BM = 128, BK = 32;
  const int tid = threadIdx.x;
  const int lane = tid & 63;
  const int wid = tid >> 6;
  const int wm = wid & 1;
  const int wn = wid >> 1;
  const int m0 = by * BM;
  const int n0 = bx * 64;
  int Meff = 0, baseE = 0;
  if (GATHER) {
    Meff = cnt[e];
    if (m0 >= Meff) return;
    baseE = ebase[e];
  }
  const unsigned short* BgE = Bg + (long)e * estrideB;
  const unsigned short* BuE = Bu + (long)e * estrideB;

  unsigned short* As = (unsigned short*)smem;  // [2][BM*BK]
  unsigned short* Bgs = As + 2 * BM * BK;      // [2][64*BK]
  unsigned short* Bus = Bgs + 2 * 64 * BK;     // [2][64*BK]

  const int lrow = lane >> 2;  // 16 rows / 1KB chunk
  const int lcol = (((lane & 3) ^ ((lrow >> 1) & 3)) << 4);  // swizzled

  const char* aP[2];
#pragma unroll
  for (int i = 0; i < 2; ++i) {
    int m = m0 + wid * 32 + i * 16 + lrow;
    long row;
    if (GATHER) {
      int mm = (m < Meff - 1) ? m : (Meff - 1);  // clamp tail to valid slot
      row = slot_token[baseE + mm];
    } else {
      row = m;
    }
    aP[i] = (const char*)A + row * (long)(K * 2) + lcol;
  }
  int nb = n0 + wid * 16 + lrow;
  const char* bgP = (const char*)BgE + (long)nb * (K * 2) + lcol;
  const char* buP = (const char*)BuE + (long)nb * (K * 2) + lcol;

  floatx4 accG[4][2], accU[4][2];
  floatx4 zero = {0.f, 0.f, 0.f, 0.f};
#pragma unroll
  for (int i = 0; i < 4; ++i)
#pragma unroll
    for (int j = 0; j < 2; ++j) { accG[i][j] = zero; accU[i][j] = zero; }

  const int ar = lane & 15;
  const int aksw = (((lane >> 4) ^ ((ar >> 1) & 3)) << 3);  // swizzled k-chunk

  auto stage = [&](int p, int k0) {
#pragma unroll
    for (int i = 0; i < 2; ++i)
      gl_lds16(aP[i] + (long)k0 * 2, &As[p * BM * BK + (wid * 32 + i * 16) * BK]);
    gl_lds16(bgP + (long)k0 * 2, &Bgs[p * 64 * BK + (wid * 16) * BK]);
    gl_lds16(buP + (long)k0 * 2, &Bus[p * 64 * BK + (wid * 16) * BK]);
  };

  stage(0, 0);
  const int NI = K / BK;
  for (int i = 0; i < NI; ++i) {
    __syncthreads();
    if (i + 1 < NI) stage((i + 1) & 1, (i + 1) * BK);
    const unsigned short* Ab = &As[(i & 1) * BM * BK];
    const unsigned short* Gb = &Bgs[(i & 1) * 64 * BK];
    const unsigned short* Ub = &Bus[(i & 1) * 64 * BK];
    short8 af[4], bgf[2], buf2[2];
#pragma unroll
    for (int tm = 0; tm < 4; ++tm)
      af[tm] = *(const short8*)&Ab[(wm * 64 + tm * 16 + ar) * BK + aksw];
#pragma unroll
    for (int tn = 0; tn < 2; ++tn) {
      bgf[tn] = *(const short8*)&Gb[(wn * 32 + tn * 16 + ar) * BK + aksw];
      buf2[tn] = *(const short8*)&Ub[(wn * 32 + tn * 16 + ar) * BK + aksw];
    }
#pragma unroll
    for (int tm = 0; tm < 4; ++tm)
#pragma unroll
      for (int tn = 0; tn < 2; ++tn) {
        accG[tm][tn] = __builtin_amdgcn_mfma_f32_16x16x32_bf16(af[tm], bgf[tn], accG[tm][tn], 0, 0, 0);
        accU[tm][tn] = __builtin_amdgcn_mfma_f32_16x16x32_bf16(af[tm], buf2[tn], accU[tm][tn], 0, 0, 0);
      }
  }

#pragma unroll
  for (int tm = 0; tm < 4; ++tm)
#pragma unroll
    for (int tn = 0; tn < 2; ++tn)
#pragma unroll
      for (int r = 0; r < 4; ++r) {
        int row = m0 + wm * 64 + tm * 16 + (lane >> 4) * 4 + r;
        int col = n0 + wn * 32 + tn * 16 + (lane & 15);
        if (!GATHER || row < Meff) {
          float g = accG[tm][tn][r];
          float u = accU[tm][tn][r];
          float act = g / (1.f + expf(-g)) * u;
          Out[(long)(baseE + row) * N + col] = f2bf(act);
        }
      }
}

// Fused launch: blocks [0,512) = shared SwiGLU (M=2048,N=2048,K=1024);
// blocks [512,1536) = expert SwiGLU (gathered, BM=128, N=512,K=1024).
__global__ __launch_bounds__(256, 2) void swiglu_fused(
    const unsigned short* __restrict__ xb, const unsigned short* __restrict__ sgate,
    const unsigned short* __restrict__ sup, unsigned short* __restrict__ act_s,
    const unsigned short* __restrict__ gup, unsigned short* __restrict__ act_e,
    const int* __restrict__ slot_token, const int* __restrict__ cnt,
    const int* __restrict__ ebase) {
  __shared__ __align__(16) char smem[32768];
  int bid = blockIdx.x;
  if (bid < 512) {
    // bx in [0,32), by in [0,16)
    swiglu_body<false>(smem, bid & 31, bid >> 5, 0, xb, sgate, sup, act_s,
                       nullptr, nullptr, nullptr, SI_DIM, H_DIM, 0);
  } else {
    int b2 = bid - 512;
    int e = b2 >> 7;
    int rem = b2 & 127;  // bx in [0,8), by in [0,16)
    swiglu_body<true>(smem, rem & 7, rem >> 3, e, xb, gup,
                      gup + (long)I_DIM * H_DIM, act_e, slot_token, cnt,
                      ebase, I_DIM, H_DIM, (long)2 * I_DIM * H_DIM);
  }
}

// ---------------------------------------------------------------------------
// Down-proj GEMM body: C = A@B^T. BM=BN=128, BK=32; 4 waves (2x2), each
// 64x64 = 4x4 tiles: 8 ds_read_b128 feeding 16 MFMA per iter (ratio 2.0).
// MODE 0: shared split-K part 0 -> OutF[row][col] = v (raw fp32)
// MODE 2: shared split-K part 1 -> OutB[row][col] = bf16(v)
// MODE 1: expert -> OutB[(baseE+row)][col] = bf16(v)
// ---------------------------------------------------------------------------
template <int MODE>
__device__ __forceinline__ void down_body(
    char* smem, int bx, int by, int e,
    const unsigned short* __restrict__ A, const unsigned short* __restrict__ B,
    float* __restrict__ OutF, unsigned short* __restrict__ OutB,
    const int* __restrict__ ebase, const int* __restrict__ cnt,
    int N, int Kstride, int kbeg, int kcnt, long estrideB) {
  const int BM = 128, BK = 32;
  const int tid = threadIdx.x;
  const int lane = tid & 63;
  const int wid = tid >> 6;
  const int wm = wid & 1;
  const int wn = wid >> 1;
  const int m0 = by * BM;
  const int n0 = bx * 128;
  int Meff = 0, baseE = 0;
  if (MODE == 1) {
    Meff = cnt[e];
    if (m0 >= Meff) return;
    baseE = ebase[e];
  }
  const unsigned short* BE = B + (long)e * estrideB;

  unsigned short* As = (unsigned short*)smem;  // [2][128*BK]
  unsigned short* Bs = As + 2 * BM * BK;       // [2][128*BK]

  const int lrow = lane >> 2;
  const int lcol = (((lane & 3) ^ ((lrow >> 1) & 3)) << 4);

  const char* aP[2];
  const char* bP[2];
#pragma unroll
  for (int i = 0; i < 2; ++i) {
    int m = m0 + wid * 32 + i * 16 + lrow;
    long arow;
    if (MODE == 1) {
      int mm = (m < Meff - 1) ? m : (Meff - 1);
      arow = baseE + mm;
    } else {
      arow = m;
    }
    aP[i] = (const char*)A + arow * (long)(Kstride * 2) + (long)kbeg * 2 + lcol;
    int n = n0 + wid * 32 + i * 16 + lrow;
    bP[i] = (const char*)BE + (long)n * (Kstride * 2) + (long)kbeg * 2 + lcol;
  }

  floatx4 acc[4][4];
  floatx4 zero = {0.f, 0.f, 0.f, 0.f};
#pragma unroll
  for (int i = 0; i < 4; ++i)
#pragma unroll
    for (int j = 0; j < 4; ++j) acc[i][j] = zero;

  const int ar = lane & 15;
  const int aksw = (((lane >> 4) ^ ((ar >> 1) & 3)) << 3);

  auto stage = [&](int p, int k0) {
#pragma unroll
    for (int i = 0; i < 2; ++i) {
      gl_lds16(aP[i] + (long)k0 * 2, &As[p * BM * BK + (wid * 32 + i * 16) * BK]);
      gl_lds16(bP[i] + (long)k0 * 2, &Bs[p * BM * BK + (wid * 32 + i * 16) * BK]);
    }
  };

  stage(0, 0);
  const int NI = kcnt / BK;
  for (int i = 0; i < NI; ++i) {
    __syncthreads();
    if (i + 1 < NI) stage((i + 1) & 1, (i + 1) * BK);
    const unsigned short* Ab = &As[(i & 1) * BM * BK];
    const unsigned short* Bb = &Bs[(i & 1) * BM * BK];
    short8 af[4], bf[4];
#pragma unroll
    for (int tm = 0; tm < 4; ++tm)
      af[tm] = *(const short8*)&Ab[(wm * 64 + tm * 16 + ar) * BK + aksw];
#pragma unroll
    for (int tn = 0; tn < 4; ++tn)
      bf[tn] = *(const short8*)&Bb[(wn * 64 + tn * 16 + ar) * BK + aksw];
#pragma unroll
    for (int tm = 0; tm < 4; ++tm)
#pragma unroll
      for (int tn = 0; tn < 4; ++tn)
        acc[tm][tn] = __builtin_amdgcn_mfma_f32_16x16x32_bf16(af[tm], bf[tn], acc[tm][tn], 0, 0, 0);
  }

#pragma unroll
  for (int tm = 0; tm < 4; ++tm)
#pragma unroll
    for (int r = 0; r < 4; ++r) {
      int row = m0 + wm * 64 + tm * 16 + (lane >> 4) * 4 + r;
#pragma unroll
      for (int tn = 0; tn < 4; ++tn) {
        int col = n0 + wn * 64 + tn * 16 + (lane & 15);
        float v = acc[tm][tn][r];
        if (MODE == 0) {
          OutF[(long)row * N + col] = v;
        } else if (MODE == 2) {
          OutB[(long)row * N + col] = f2bf(v);
        } else if (row < Meff) {
          OutB[(long)(baseE + row) * N + col] = f2bf(v);
        }
      }
    }
}

// Fused launch: [0,128) shared down K[0,1024) -> out (raw fp32);
// [128,256) shared down K[1024,2048) -> spart (bf16);
// [256,1280) expert down -> eout (bf16).
__global__ __launch_bounds__(256, 2) void down_fused(
    const unsigned short* __restrict__ act_s, const unsigned short* __restrict__ sdown,
    float* __restrict__ out, unsigned short* __restrict__ spart,
    const unsigned short* __restrict__ act_e, const unsigned short* __restrict__ downw,
    unsigned short* __restrict__ eout, const int* __restrict__ ebase,
    const int* __restrict__ cnt) {
  __shared__ __align__(16) char smem[32768];
  int bid = blockIdx.x;
  if (bid < 128) {
    down_body<0>(smem, bid & 7, bid >> 3, 0, act_s, sdown, out, nullptr,
                 nullptr, nullptr, H_DIM, SI_DIM, 0, 1024, 0);
  } else if (bid < 256) {
    int b = bid - 128;
    down_body<2>(smem, b & 7, b >> 3, 0, act_s, sdown, nullptr, spart,
                 nullptr, nullptr, H_DIM, SI_DIM, 1024, 1024, 0);
  } else {
    int b2 = bid - 256;
    int e = b2 >> 7;
    int rem = b2 & 127;  // bx in [0,8), by in [0,16)
    down_body<1>(smem, rem & 7, rem >> 3, e, act_e, downw, nullptr, eout,
                 ebase, cnt, H_DIM, I_DIM, 0, I_DIM, (long)H_DIM * I_DIM);
  }
}

// ---------------------------------------------------------------------------
// Combine: out[t][h] = sg[t]*(p0 + p1) + w0*eout[s0][h] + w1*eout[s1][h].
// p0 = raw fp32 in out, p1 = bf16 in spart. One block per token.
// ---------------------------------------------------------------------------
__global__ __launch_bounds__(256) void combine_kernel(
    float* __restrict__ out, const unsigned short* __restrict__ spart,
    const unsigned short* __restrict__ eout, const float* __restrict__ sg,
    const float2* __restrict__ w01, const int* __restrict__ tok_slot) {
  int t = blockIdx.x;
  int c = threadIdx.x;  // 256 threads x 4 elems = 1024
  float sgr = sg[t];
  float2 wr = w01[t];
  int s0 = tok_slot[2 * t];
  int s1 = tok_slot[2 * t + 1];
  ushort4 p1 = ((const ushort4*)(spart + (long)t * H_DIM))[c];
  ushort4 e0 = ((const ushort4*)(eout + (long)s0 * H_DIM))[c];
  ushort4 e1 = ((const ushort4*)(eout + (long)s1 * H_DIM))[c];
  float4* op = &((float4*)(out + (long)t * H_DIM))[c];
  float4 o = *op;
  o.x = sgr * (o.x + bf2f(p1.x)) + wr.x * bf2f(e0.x) + wr.y * bf2f(e1.x);
  o.y = sgr * (o.y + bf2f(p1.y)) + wr.x * bf2f(e0.y) + wr.y * bf2f(e1.y);
  o.z = sgr * (o.z + bf2f(p1.z)) + wr.x * bf2f(e0.z) + wr.y * bf2f(e1.z);
  o.w = sgr * (o.w + bf2f(p1.w)) + wr.x * bf2f(e0.w) + wr.y * bf2f(e1.w);
  *op = o;
}

// ---------------------------------------------------------------------------
// Workspace map (bytes), total ~60.1 MB (ws proven >= 67.25 MB in round 1):
//   0         xb       bf16[2048][1024]     4,194,304  (reused as spart by down)
//   4194304   gup_b    bf16[8][1024][1024] 16,777,216
//  20971520   down_b   bf16[8][1024][512]   8,388,608
//  29360128   sgate_b  bf16[2048][1024]     4,194,304
//  33554432   sup_b    bf16[2048][1024]     4,194,304
//  37748736   sdown_b  bf16[1024][2048]     4,194,304
//  41943040   act_s    bf16[2048][2048]     8,388,608
//  50331648   act_e    bf16[4096][512]      4,194,304
//  54525952   eout     bf16[4096][1024]     8,388,608
//  62914560   sg       f32[2048]
//  62922752   top2     int[2048]
//  62930944   w01      float2[2048]
//  62947328   cnt      int[8] (pad)
//  62947584   ebase    int[8] (pad)
//  62947840   slot_token int[4096]
//  62964224   tok_slot int[4096]
// ---------------------------------------------------------------------------
extern "C" void kernel_launch(void* const* d_in, const int* in_sizes, int n_in,
                              void* d_out, int out_size, void* d_ws, size_t ws_size,
                              hipStream_t stream) {
  const float* x = (const float*)d_in[0];
  const float* rw = (const float*)d_in[1];
  const float* gup = (const float*)d_in[2];
  const float* dwn = (const float*)d_in[3];
  const float* sgw = (const float*)d_in[4];
  const float* suw = (const float*)d_in[5];
  const float* sdw = (const float*)d_in[6];
  const float* segw = (const float*)d_in[7];
  float* out = (float*)d_out;

  char* w = (char*)d_ws;
  unsigned short* xb = (unsigned short*)(w + 0);
  unsigned short* gup_b = (unsigned short*)(w + 4194304L);
  unsigned short* down_b = (unsigned short*)(w + 20971520L);
  unsigned short* sgate_b = (unsigned short*)(w + 29360128L);
  unsigned short* sup_b = (unsigned short*)(w + 33554432L);
  unsigned short* sdown_b = (unsigned short*)(w + 37748736L);
  unsigned short* act_s = (unsigned short*)(w + 41943040L);
  unsigned short* act_e = (unsigned short*)(w + 50331648L);
  unsigned short* eout = (unsigned short*)(w + 54525952L);
  float* sg = (float*)(w + 62914560L);
  int* top2 = (int*)(w + 62922752L);
  float2* w01 = (float2*)(w + 62930944L);
  int* cnt = (int*)(w + 62947328L);
  int* ebase = (int*)(w + 62947584L);
  int* slot_token = (int*)(w + 62947840L);
  int* tok_slot = (int*)(w + 62964224L);
  unsigned short* spart = xb;  // xb is dead after swiglu_fused; reuse for split-K partial

  // router (512 blocks, first) + cast (20480 blocks) in one launch
  cast_router<<<20992, 256, 0, stream>>>(x, rw, segw, gup, dwn, sgw, suw, sdw,
                                         xb, gup_b, down_b, sgate_b, sup_b,
                                         sdown_b, top2, w01, sg);
  build_lists<<<E_NUM, 256, 0, stream>>>(top2, cnt, ebase, slot_token, tok_slot);
  // fused shared+expert SwiGLU
  swiglu_fused<<<1536, 256, 0, stream>>>(xb, sgate_b, sup_b, act_s, gup_b,
                                         act_e, slot_token, cnt, ebase);
  // fused shared (split-K x2) + expert down-proj
  down_fused<<<1280, 256, 0, stream>>>(act_s, sdown_b, out, spart, act_e,
                                       down_b, eout, ebase, cnt);
  // out = sg*(p0+p1) + w0*eout[s0] + w1*eout[s1]
  combine_kernel<<<T_TOK, 256, 0, stream>>>(out, spart, eout, sg, w01, tok_slot);
}

// Round 7
// 201.122 us; speedup vs baseline: 1.6886x; 1.0361x over previous
//
#include <hip/hip_runtime.h>

// Problem constants (B=2,S=1024 -> T=2048; H=1024, I=512, SI=2048, E=8, TOPK=2)
#define T_TOK 2048
#define H_DIM 1024
#define I_DIM 512
#define SI_DIM 2048
#define E_NUM 8
#define NSLOT 4096  // total expert slots: exactly 2 per token

typedef __attribute__((ext_vector_type(8))) short short8;   // 8 x bf16 (4 VGPRs)
typedef __attribute__((ext_vector_type(4))) float floatx4;  // MFMA C/D

// fp32 -> bf16 round-to-nearest-even
__device__ inline unsigned short f2bf(float f) {
  unsigned u = __builtin_bit_cast(unsigned, f);
  u = (u + 0x7FFFu + ((u >> 16) & 1u)) >> 16;
  return (unsigned short)u;
}
__device__ inline float bf2f(unsigned short u) {
  return __builtin_bit_cast(float, (unsigned)u << 16);
}

// async global->LDS, 16B per lane; LDS dest = wave-uniform base + lane*16
__device__ inline void gl_lds16(const void* g, void* l) {
  __builtin_amdgcn_global_load_lds(
      (const __attribute__((address_space(1))) unsigned int*)g,
      (__attribute__((address_space(3))) unsigned int*)l, 16, 0, 0);
}

// ---------------------------------------------------------------------------
// Fused cast + router. Blocks [0,512): router (latency-bound, dispatched
// first so it overlaps the BW-bound cast flood). Blocks [512,20992): cast.
// ---------------------------------------------------------------------------
__global__ __launch_bounds__(256) void cast_router(
    const float* __restrict__ x, const float* __restrict__ rw,
    const float* __restrict__ segw,
    const float* __restrict__ s1, const float* __restrict__ s2,
    const float* __restrict__ s3, const float* __restrict__ s4,
    const float* __restrict__ s5,
    unsigned short* __restrict__ d0, unsigned short* __restrict__ d1,
    unsigned short* __restrict__ d2, unsigned short* __restrict__ d3,
    unsigned short* __restrict__ d4, unsigned short* __restrict__ d5,
    int* __restrict__ top2, float2* __restrict__ w01, float* __restrict__ sg) {
  const int bid = blockIdx.x;
  if (bid < 512) {
    // ---- router: one wave per token, fp32 logits (matches ref numerics) ----
    int t = bid * 4 + (threadIdx.x >> 6);
    int lane = threadIdx.x & 63;
    const float* xt = x + (long)t * H_DIM;
    float xv[16];
#pragma unroll
    for (int j = 0; j < 16; ++j) xv[j] = xt[j * 64 + lane];
    float dots[9];
#pragma unroll
    for (int e = 0; e < 8; ++e) {
      const float* w = rw + e * H_DIM;
      float s = 0.f;
#pragma unroll
      for (int j = 0; j < 16; ++j) s += xv[j] * w[j * 64 + lane];
      dots[e] = s;
    }
    {
      float s = 0.f;
#pragma unroll
      for (int j = 0; j < 16; ++j) s += xv[j] * segw[j * 64 + lane];
      dots[8] = s;
    }
#pragma unroll
    for (int off = 32; off > 0; off >>= 1) {
#pragma unroll
      for (int e = 0; e < 9; ++e) dots[e] += __shfl_xor(dots[e], off, 64);
    }
    if (lane == 0) {
      int e0 = 0;
      for (int e = 1; e < 8; ++e)
        if (dots[e] > dots[e0]) e0 = e;
      int e1 = (e0 == 0) ? 1 : 0;
      for (int e = 0; e < 8; ++e)
        if (e != e0 && dots[e] > dots[e1]) e1 = e;
      float p1 = expf(dots[e1] - dots[e0]);
      top2[t] = e0 | (e1 << 8);
      w01[t] = make_float2(1.f / (1.f + p1), p1 / (1.f + p1));
      sg[t] = 1.f / (1.f + expf(-dots[8]));
    }
  } else {
    // ---- cast: 6 fp32 segments -> bf16, 4 elems/thread ----
    long g = (long)(bid - 512) * 256 + threadIdx.x;
    const float* s;
    unsigned short* d;
    long off;
    if (g < 524288L)       { s = x;  d = d0; off = g; }            // x
    else if (g < 2621440L) { s = s1; d = d1; off = g - 524288L; }  // gate_up
    else if (g < 3670016L) { s = s2; d = d2; off = g - 2621440L; } // down
    else if (g < 4194304L) { s = s3; d = d3; off = g - 3670016L; } // shared_gate
    else if (g < 4718592L) { s = s4; d = d4; off = g - 4194304L; } // shared_up
    else                   { s = s5; d = d5; off = g - 4718592L; } // shared_down
    float4 v = ((const float4*)s)[off];
    ushort4 o;
    o.x = f2bf(v.x); o.y = f2bf(v.y); o.z = f2bf(v.z); o.w = f2bf(v.w);
    ((ushort4*)d)[off] = o;
  }
}

// ---------------------------------------------------------------------------
// Router phase 2: one block per expert; block-wide scan -> compact slot list
// (global base = #assignments to experts < e) + tok_slot back-pointers.
// ---------------------------------------------------------------------------
__global__ __launch_bounds__(256) void build_lists(
    const int* __restrict__ top2, int* __restrict__ cnt, int* __restrict__ ebase,
    int* __restrict__ slot_token, int* __restrict__ tok_slot) {
  const int e = blockIdx.x;
  const int tid = threadIdx.x;
  const int lane = tid & 63, wid = tid >> 6;
  __shared__ int wsum[4], wbelow[4];
  const int base_t = tid * 8;  // 2048 / 256
  int mk[8], kk[8];
  int c = 0, below = 0;
#pragma unroll
  for (int j = 0; j < 8; ++j) {
    int p = top2[base_t + j];
    int e0 = p & 0xFF, e1 = (p >> 8) & 0xFF;
    below += (e0 < e) + (e1 < e);
    int m = 0, k = 0;
    if (e0 == e) { m = 1; k = 0; }
    else if (e1 == e) { m = 1; k = 1; }
    mk[j] = m; kk[j] = k;
    c += m;
  }
  int inc = c;
#pragma unroll
  for (int off = 1; off < 64; off <<= 1) {
    int n = __shfl_up(inc, off, 64);
    if (lane >= off) inc += n;
  }
  int bsum = below;
#pragma unroll
  for (int off = 32; off > 0; off >>= 1) bsum += __shfl_xor(bsum, off, 64);
  if (lane == 63) wsum[wid] = inc;
  if (lane == 0) wbelow[wid] = bsum;
  __syncthreads();
  int woff = 0;
#pragma unroll
  for (int i = 0; i < 4; ++i)
    if (i < wid) woff += wsum[i];
  int baseE = wbelow[0] + wbelow[1] + wbelow[2] + wbelow[3];
  int pos = baseE + woff + inc - c;
#pragma unroll
  for (int j = 0; j < 8; ++j) {
    if (mk[j]) {
      slot_token[pos] = base_t + j;
      tok_slot[2 * (base_t + j) + kk[j]] = pos;
      pos++;
    }
  }
  if (tid == 255) cnt[e] = woff + inc;
  if (tid == 0) ebase[e] = baseE;
}

// ---------------------------------------------------------------------------
// Fused SwiGLU GEMM body: act = silu(A@Bg^T)*(A@Bu^T), bf16, fp32 acc.
// BM=128, BN=128, BK=32. 4 waves (2x2): each covers 64 rows x 64 cols (G+U).
// Per iter per wave: 12 ds_read_b128 feeding 32 MFMA (0.375 reads/MFMA).
// Double-buffered LDS (1 barrier/iter) + XOR bank swizzle (0 conflicts).
// Grid sized so ALL active blocks are co-resident (no serial generations).
// ---------------------------------------------------------------------------
template <bool GATHER>
__device__ __forceinline__ void swiglu_body(
    char* smem, int bx, int by, int e,
    const unsigned short* __restrict__ A, const unsigned short* __restrict__ Bg,
    const unsigned short* __restrict__ Bu, unsigned short* __restrict__ Out,
    const int* __restrict__ slot_token, const int* __restrict__ cnt,
    const int* __restrict__ ebase, int N, int K, long estrideB) {
  const int BM = 128, BK = 32;
  const int TILE = BM * BK;  // ushorts per buffer (A, Bg, Bu all 128x32)
  const int tid = threadIdx.x;
  const int lane = tid & 63;
  const int wid = tid >> 6;
  const int wm = wid & 1;
  const int wn = wid >> 1;
  const int m0 = by * BM;
  const int n0 = bx * 128;
  int Meff = 0, baseE = 0;
  if (GATHER) {
    Meff = cnt[e];
    if (m0 >= Meff) return;
    baseE = ebase[e];
  }
  const unsigned short* BgE = Bg + (long)e * estrideB;
  const unsigned short* BuE = Bu + (long)e * estrideB;

  unsigned short* As = (unsigned short*)smem;  // [2][128*32]
  unsigned short* Bgs = As + 2 * TILE;         // [2][128*32]
  unsigned short* Bus = Bgs + 2 * TILE;        // [2][128*32]

  const int lrow = lane >> 2;  // 16 rows / 1KB chunk
  const int lcol = (((lane & 3) ^ ((lrow >> 1) & 3)) << 4);  // swizzled

  const char* aP[2];
  const char* bgP[2];
  const char* buP[2];
#pragma unroll
  for (int i = 0; i < 2; ++i) {
    int m = m0 + wid * 32 + i * 16 + lrow;
    long row;
    if (GATHER) {
      int mm = (m < Meff - 1) ? m : (Meff - 1);  // clamp tail to valid slot
      row = slot_token[baseE + mm];
    } else {
      row = m;
    }
    aP[i] = (const char*)A + row * (long)(K * 2) + lcol;
    int n = n0 + wid * 32 + i * 16 + lrow;
    bgP[i] = (const char*)BgE + (long)n * (K * 2) + lcol;
    buP[i] = (const char*)BuE + (long)n * (K * 2) + lcol;
  }

  floatx4 accG[4][4], accU[4][4];
  floatx4 zero = {0.f, 0.f, 0.f, 0.f};
#pragma unroll
  for (int i = 0; i < 4; ++i)
#pragma unroll
    for (int j = 0; j < 4; ++j) { accG[i][j] = zero; accU[i][j] = zero; }

  const int ar = lane & 15;
  const int aksw = (((lane >> 4) ^ ((ar >> 1) & 3)) << 3);  // swizzled k-chunk

  auto stage = [&](int p, int k0) {
#pragma unroll
    for (int i = 0; i < 2; ++i) {
      gl_lds16(aP[i] + (long)k0 * 2, &As[p * TILE + (wid * 32 + i * 16) * BK]);
      gl_lds16(bgP[i] + (long)k0 * 2, &Bgs[p * TILE + (wid * 32 + i * 16) * BK]);
      gl_lds16(buP[i] + (long)k0 * 2, &Bus[p * TILE + (wid * 32 + i * 16) * BK]);
    }
  };

  stage(0, 0);
  const int NI = K / BK;
  for (int i = 0; i < NI; ++i) {
    __syncthreads();
    if (i + 1 < NI) stage((i + 1) & 1, (i + 1) * BK);
    const unsigned short* Ab = &As[(i & 1) * TILE];
    const unsigned short* Gb = &Bgs[(i & 1) * TILE];
    const unsigned short* Ub = &Bus[(i & 1) * TILE];
    short8 af[4], bgf[4], buf2[4];
#pragma unroll
    for (int tm = 0; tm < 4; ++tm)
      af[tm] = *(const short8*)&Ab[(wm * 64 + tm * 16 + ar) * BK + aksw];
#pragma unroll
    for (int tn = 0; tn < 4; ++tn) {
      bgf[tn] = *(const short8*)&Gb[(wn * 64 + tn * 16 + ar) * BK + aksw];
      buf2[tn] = *(const short8*)&Ub[(wn * 64 + tn * 16 + ar) * BK + aksw];
    }
#pragma unroll
    for (int tm = 0; tm < 4; ++tm)
#pragma unroll
      for (int tn = 0; tn < 4; ++tn) {
        accG[tm][tn] = __builtin_amdgcn_mfma_f32_16x16x32_bf16(af[tm], bgf[tn], accG[tm][tn], 0, 0, 0);
        accU[tm][tn] = __builtin_amdgcn_mfma_f32_16x16x32_bf16(af[tm], buf2[tn], accU[tm][tn], 0, 0, 0);
      }
  }

#pragma unroll
  for (int tm = 0; tm < 4; ++tm)
#pragma unroll
    for (int tn = 0; tn < 4; ++tn)
#pragma unroll
      for (int r = 0; r < 4; ++r) {
        int row = m0 + wm * 64 + tm * 16 + (lane >> 4) * 4 + r;
        int col = n0 + wn * 64 + tn * 16 + (lane & 15);
        if (!GATHER || row < Meff) {
          float g = accG[tm][tn][r];
          float u = accU[tm][tn][r];
          float act = g / (1.f + expf(-g)) * u;
          Out[(long)(baseE + row) * N + col] = f2bf(act);
        }
      }
}

// Fused launch: blocks [0,256) = shared SwiGLU (M=2048,N=2048,K=1024);
// blocks [256,768) = expert SwiGLU (gathered, N=512,K=1024; ~128 active).
__global__ __launch_bounds__(256, 2) void swiglu_fused(
    const unsigned short* __restrict__ xb, const unsigned short* __restrict__ sgate,
    const unsigned short* __restrict__ sup, unsigned short* __restrict__ act_s,
    const unsigned short* __restrict__ gup, unsigned short* __restrict__ act_e,
    const int* __restrict__ slot_token, const int* __restrict__ cnt,
    const int* __restrict__ ebase) {
  __shared__ __align__(16) char smem[49152];
  int bid = blockIdx.x;
  if (bid < 256) {
    // bx in [0,16), by in [0,16)
    swiglu_body<false>(smem, bid & 15, bid >> 4, 0, xb, sgate, sup, act_s,
                       nullptr, nullptr, nullptr, SI_DIM, H_DIM, 0);
  } else {
    int b2 = bid - 256;
    int e = b2 >> 6;
    int rem = b2 & 63;  // bx in [0,4), by in [0,16)
    swiglu_body<true>(smem, rem & 3, rem >> 2, e, xb, gup,
                      gup + (long)I_DIM * H_DIM, act_e, slot_token, cnt,
                      ebase, I_DIM, H_DIM, (long)2 * I_DIM * H_DIM);
  }
}

// ---------------------------------------------------------------------------
// Down-proj GEMM body: C = A@B^T. BM=128, BN=256, BK=32; 4 waves (2x2),
// each 64x128: 12 ds_read_b128 feeding 32 MFMA per iter (0.375 reads/MFMA).
// MODE 0: shared split-K part 0 -> OutF[row][col] = v (raw fp32)
// MODE 2: shared split-K part 1 -> OutB[row][col] = bf16(v)
// MODE 1: expert -> OutB[(baseE+row)][col] = bf16(v)
// ---------------------------------------------------------------------------
template <int MODE>
__device__ __forceinline__ void down_body(
    char* smem, int bx, int by, int e,
    const unsigned short* __restrict__ A, const unsigned short* __restrict__ B,
    float* __restrict__ OutF, unsigned short* __restrict__ OutB,
    const int* __restrict__ ebase, const int* __restrict__ cnt,
    int N, int Kstride, int kbeg, int kcnt, long estrideB) {
  const int BM = 128, BK = 32;
  const int ATILE = BM * BK;       // 4096 ushorts
  const int BTILE = 256 * BK;      // 8192 ushorts
  const int tid = threadIdx.x;
  const int lane = tid & 63;
  const int wid = tid >> 6;
  const int wm = wid & 1;
  const int wn = wid >> 1;
  const int m0 = by * BM;
  const int n0 = bx * 256;
  int Meff = 0, baseE = 0;
  if (MODE == 1) {
    Meff = cnt[e];
    if (m0 >= Meff) return;
    baseE = ebase[e];
  }
  const unsigned short* BE = B + (long)e * estrideB;

  unsigned short* As = (unsigned short*)smem;  // [2][128*32]
  unsigned short* Bs = As + 2 * ATILE;         // [2][256*32]

  const int lrow = lane >> 2;
  const int lcol = (((lane & 3) ^ ((lrow >> 1) & 3)) << 4);

  const char* aP[2];
  const char* bP[4];
#pragma unroll
  for (int i = 0; i < 2; ++i) {
    int m = m0 + wid * 32 + i * 16 + lrow;
    long arow;
    if (MODE == 1) {
      int mm = (m < Meff - 1) ? m : (Meff - 1);
      arow = baseE + mm;
    } else {
      arow = m;
    }
    aP[i] = (const char*)A + arow * (long)(Kstride * 2) + (long)kbeg * 2 + lcol;
  }
#pragma unroll
  for (int i = 0; i < 4; ++i) {
    int n = n0 + wid * 64 + i * 16 + lrow;
    bP[i] = (const char*)BE + (long)n * (Kstride * 2) + (long)kbeg * 2 + lcol;
  }

  floatx4 acc[4][8];
  floatx4 zero = {0.f, 0.f, 0.f, 0.f};
#pragma unroll
  for (int i = 0; i < 4; ++i)
#pragma unroll
    for (int j = 0; j < 8; ++j) acc[i][j] = zero;

  const int ar = lane & 15;
  const int aksw = (((lane >> 4) ^ ((ar >> 1) & 3)) << 3);

  auto stage = [&](int p, int k0) {
#pragma unroll
    for (int i = 0; i < 2; ++i)
      gl_lds16(aP[i] + (long)k0 * 2, &As[p * ATILE + (wid * 32 + i * 16) * BK]);
#pragma unroll
    for (int i = 0; i < 4; ++i)
      gl_lds16(bP[i] + (long)k0 * 2, &Bs[p * BTILE + (wid * 64 + i * 16) * BK]);
  };

  stage(0, 0);
  const int NI = kcnt / BK;
  for (int i = 0; i < NI; ++i) {
    __syncthreads();
    if (i + 1 < NI) stage((i + 1) & 1, (i + 1) * BK);
    const unsigned short* Ab = &As[(i & 1) * ATILE];
    const unsigned short* Bb = &Bs[(i & 1) * BTILE];
    short8 af[4], bf[8];
#pragma unroll
    for (int tm = 0; tm < 4; ++tm)
      af[tm] = *(const short8*)&Ab[(wm * 64 + tm * 16 + ar) * BK + aksw];
#pragma unroll
    for (int tn = 0; tn < 8; ++tn)
      bf[tn] = *(const short8*)&Bb[(wn * 128 + tn * 16 + ar) * BK + aksw];
#pragma unroll
    for (int tm = 0; tm < 4; ++tm)
#pragma unroll
      for (int tn = 0; tn < 8; ++tn)
        acc[tm][tn] = __builtin_amdgcn_mfma_f32_16x16x32_bf16(af[tm], bf[tn], acc[tm][tn], 0, 0, 0);
  }

#pragma unroll
  for (int tm = 0; tm < 4; ++tm)
#pragma unroll
    for (int r = 0; r < 4; ++r) {
      int row = m0 + wm * 64 + tm * 16 + (lane >> 4) * 4 + r;
#pragma unroll
      for (int tn = 0; tn < 8; ++tn) {
        int col = n0 + wn * 128 + tn * 16 + (lane & 15);
        float v = acc[tm][tn][r];
        if (MODE == 0) {
          OutF[(long)row * N + col] = v;
        } else if (MODE == 2) {
          OutB[(long)row * N + col] = f2bf(v);
        } else if (row < Meff) {
          OutB[(long)(baseE + row) * N + col] = f2bf(v);
        }
      }
    }
}

// Fused launch: [0,64) shared down K[0,1024) -> out (raw fp32);
// [64,128) shared down K[1024,2048) -> spart (bf16);
// [128,640) expert down -> eout (bf16, ~128 active).
__global__ __launch_bounds__(256, 2) void down_fused(
    const unsigned short* __restrict__ act_s, const unsigned short* __restrict__ sdown,
    float* __restrict__ out, unsigned short* __restrict__ spart,
    const unsigned short* __restrict__ act_e, const unsigned short* __restrict__ downw,
    unsigned short* __restrict__ eout, const int* __restrict__ ebase,
    const int* __restrict__ cnt) {
  __shared__ __align__(16) char smem[49152];
  int bid = blockIdx.x;
  if (bid < 64) {
    down_body<0>(smem, bid & 3, bid >> 2, 0, act_s, sdown, out, nullptr,
                 nullptr, nullptr, H_DIM, SI_DIM, 0, 1024, 0);
  } else if (bid < 128) {
    int b = bid - 64;
    down_body<2>(smem, b & 3, b >> 2, 0, act_s, sdown, nullptr, spart,
                 nullptr, nullptr, H_DIM, SI_DIM, 1024, 1024, 0);
  } else {
    int b2 = bid - 128;
    int e = b2 >> 6;
    int rem = b2 & 63;  // bx in [0,4), by in [0,16)
    down_body<1>(smem, rem & 3, rem >> 2, e, act_e, downw, nullptr, eout,
                 ebase, cnt, H_DIM, I_DIM, 0, I_DIM, (long)H_DIM * I_DIM);
  }
}

// ---------------------------------------------------------------------------
// Combine: out[t][h] = sg[t]*(p0 + p1) + w0*eout[s0][h] + w1*eout[s1][h].
// p0 = raw fp32 in out, p1 = bf16 in spart. One block per token.
// ---------------------------------------------------------------------------
__global__ __launch_bounds__(256) void combine_kernel(
    float* __restrict__ out, const unsigned short* __restrict__ spart,
    const unsigned short* __restrict__ eout, const float* __restrict__ sg,
    const float2* __restrict__ w01, const int* __restrict__ tok_slot) {
  int t = blockIdx.x;
  int c = threadIdx.x;  // 256 threads x 4 elems = 1024
  float sgr = sg[t];
  float2 wr = w01[t];
  int s0 = tok_slot[2 * t];
  int s1 = tok_slot[2 * t + 1];
  ushort4 p1 = ((const ushort4*)(spart + (long)t * H_DIM))[c];
  ushort4 e0 = ((const ushort4*)(eout + (long)s0 * H_DIM))[c];
  ushort4 e1 = ((const ushort4*)(eout + (long)s1 * H_DIM))[c];
  float4* op = &((float4*)(out + (long)t * H_DIM))[c];
  float4 o = *op;
  o.x = sgr * (o.x + bf2f(p1.x)) + wr.x * bf2f(e0.x) + wr.y * bf2f(e1.x);
  o.y = sgr * (o.y + bf2f(p1.y)) + wr.x * bf2f(e0.y) + wr.y * bf2f(e1.y);
  o.z = sgr * (o.z + bf2f(p1.z)) + wr.x * bf2f(e0.z) + wr.y * bf2f(e1.z);
  o.w = sgr * (o.w + bf2f(p1.w)) + wr.x * bf2f(e0.w) + wr.y * bf2f(e1.w);
  *op = o;
}

// ---------------------------------------------------------------------------
// Workspace map (bytes), total ~63.0 MB (ws proven >= 67.25 MB in round 1):
//   0         xb       bf16[2048][1024]     (reused as spart by down split-K)
//   4194304   gup_b    bf16[8][1024][1024]
//  20971520   down_b   bf16[8][1024][512]
//  29360128   sgate_b  bf16[2048][1024]
//  33554432   sup_b    bf16[2048][1024]
//  37748736   sdown_b  bf16[1024][2048]
//  41943040   act_s    bf16[2048][2048]
//  50331648   act_e    bf16[4096][512]
//  54525952   eout     bf16[4096][1024]
//  62914560   sg / top2 / w01 / cnt / ebase / slot_token / tok_slot
// ---------------------------------------------------------------------------
extern "C" void kernel_launch(void* const* d_in, const int* in_sizes, int n_in,
                              void* d_out, int out_size, void* d_ws, size_t ws_size,
                              hipStream_t stream) {
  const float* x = (const float*)d_in[0];
  const float* rw = (const float*)d_in[1];
  const float* gup = (const float*)d_in[2];
  const float* dwn = (const float*)d_in[3];
  const float* sgw = (const float*)d_in[4];
  const float* suw = (const float*)d_in[5];
  const float* sdw = (const float*)d_in[6];
  const float* segw = (const float*)d_in[7];
  float* out = (float*)d_out;

  char* w = (char*)d_ws;
  unsigned short* xb = (unsigned short*)(w + 0);
  unsigned short* gup_b = (unsigned short*)(w + 4194304L);
  unsigned short* down_b = (unsigned short*)(w + 20971520L);
  unsigned short* sgate_b = (unsigned short*)(w + 29360128L);
  unsigned short* sup_b = (unsigned short*)(w + 33554432L);
  unsigned short* sdown_b = (unsigned short*)(w + 37748736L);
  unsigned short* act_s = (unsigned short*)(w + 41943040L);
  unsigned short* act_e = (unsigned short*)(w + 50331648L);
  unsigned short* eout = (unsigned short*)(w + 54525952L);
  float* sg = (float*)(w + 62914560L);
  int* top2 = (int*)(w + 62922752L);
  float2* w01 = (float2*)(w + 62930944L);
  int* cnt = (int*)(w + 62947328L);
  int* ebase = (int*)(w + 62947584L);
  int* slot_token = (int*)(w + 62947840L);
  int* tok_slot = (int*)(w + 62964224L);
  unsigned short* spart = xb;  // xb dead after swiglu_fused; reuse for split-K partial

  // router (512 blocks, first) + cast (20480 blocks) in one launch
  cast_router<<<20992, 256, 0, stream>>>(x, rw, segw, gup, dwn, sgw, suw, sdw,
                                         xb, gup_b, down_b, sgate_b, sup_b,
                                         sdown_b, top2, w01, sg);
  build_lists<<<E_NUM, 256, 0, stream>>>(top2, cnt, ebase, slot_token, tok_slot);
  // fused shared+expert SwiGLU (single residency generation)
  swiglu_fused<<<768, 256, 0, stream>>>(xb, sgate_b, sup_b, act_s, gup_b,
                                        act_e, slot_token, cnt, ebase);
  // fused shared (split-K x2) + expert down-proj (single generation)
  down_fused<<<640, 256, 0, stream>>>(act_s, sdown_b, out, spart, act_e,
                                      down_b, eout, ebase, cnt);
  // out = sg*(p0+p1) + w0*eout[s0] + w1*eout[s1]
  combine_kernel<<<T_TOK, 256, 0, stream>>>(out, spart, eout, sg, w01, tok_slot);
}